// Round 4
// baseline (1746.459 us; speedup 1.0000x reference)
//
#include <hip/hip_runtime.h>
#include <cstddef>

#define Pp    3
#define Cc    64
#define IMGi  48
#define Gg    16
#define Dd    576
#define NHh   12
#define HDd   48
#define HIDh  2304
#define NLl   4
#define Ss    256
#define Bb    4
#define Mm    1024          // S*B tokens
#define EPSf  1e-5f
#define NJOBS 43

typedef short short8 __attribute__((ext_vector_type(8)));
typedef short short4v __attribute__((ext_vector_type(4)));
typedef float f32x4  __attribute__((ext_vector_type(4)));

struct QJobs { const float* ptr[NJOBS]; int n[NJOBS]; int off[NJOBS]; };

// float -> bf16 (RNE), bit-level
__device__ __forceinline__ short f2bf(float f) {
  unsigned u = __float_as_uint(f);
  u = u + 0x7fffu + ((u >> 16) & 1u);
  return (short)(u >> 16);
}

// async global->LDS, 16B per lane. dst must be wave-uniform; HW adds lane*16.
typedef __attribute__((address_space(3))) unsigned lds_u32;
typedef __attribute__((address_space(1))) const unsigned glob_u32;
__device__ __forceinline__ void gload_lds16(const void* g, void* l) {
  __builtin_amdgcn_global_load_lds((glob_u32*)g, (lds_u32*)l, 16, 0, 0);
}

// ---------------- small utility kernels ----------------

__global__ void k_zero(float* p, int n) {
  int i = blockIdx.x * blockDim.x + threadIdx.x;
  if (i < n) p[i] = 0.f;
}

// 4-deep MLP: 4 independent strided float4 loads in flight per iteration
__global__ void k_abssum(QJobs jobs, float* absum) {
  int job = blockIdx.x >> 6, blk = blockIdx.x & 63;
  const float4* p4 = (const float4*)jobs.ptr[job];
  int n4 = jobs.n[job] >> 2;
  float s0 = 0.f, s1 = 0.f, s2 = 0.f, s3 = 0.f;
  for (int i = blk * 1024 + threadIdx.x; i < n4; i += 64 * 1024) {
    float4 v = p4[i];
    s0 += fabsf(v.x) + fabsf(v.y) + fabsf(v.z) + fabsf(v.w);
    int i1 = i + 256;
    if (i1 < n4) { float4 w = p4[i1]; s1 += fabsf(w.x) + fabsf(w.y) + fabsf(w.z) + fabsf(w.w); }
    int i2 = i + 512;
    if (i2 < n4) { float4 w = p4[i2]; s2 += fabsf(w.x) + fabsf(w.y) + fabsf(w.z) + fabsf(w.w); }
    int i3 = i + 768;
    if (i3 < n4) { float4 w = p4[i3]; s3 += fabsf(w.x) + fabsf(w.y) + fabsf(w.z) + fabsf(w.w); }
  }
  float s = (s0 + s1) + (s2 + s3);
  #pragma unroll
  for (int o = 32; o; o >>= 1) s += __shfl_xor(s, o);
  __shared__ float red[4];
  if ((threadIdx.x & 63) == 0) red[threadIdx.x >> 6] = s;
  __syncthreads();
  if (threadIdx.x == 0) atomicAdd(&absum[job], (red[0] + red[1]) + (red[2] + red[3]));
}

__global__ void k_alpha(QJobs jobs, const float* absum, float* alpha, float* inva) {
  int j = threadIdx.x;
  if (j < NJOBS) {
    float a = 2.f * (absum[j] / (float)jobs.n[j]) / sqrtf(7.f);
    alpha[j] = a;
    inva[j] = 1.f / a;
  }
}

// pre-quantize all weights: wq = bf16( rint(clamp(w/alpha,-8,7)) ), 2-deep MLP
__global__ void k_quant(QJobs jobs, const float* __restrict__ inva, short* __restrict__ wq) {
  int job = blockIdx.x >> 7, blk = blockIdx.x & 127;
  const float* p = jobs.ptr[job];
  int n8 = jobs.n[job] >> 3;
  short* dst = wq + (size_t)jobs.off[job];
  float ia = inva[job];
  for (int i = blk * 512 + threadIdx.x; i < n8; i += 128 * 512) {
    const float4* p4 = (const float4*)(p + (size_t)i * 8);
    float4 w0 = p4[0], w1 = p4[1];
    int i1 = i + 256;
    float4 w2, w3;
    bool has2 = i1 < n8;
    if (has2) { const float4* q4 = (const float4*)(p + (size_t)i1 * 8); w2 = q4[0]; w3 = q4[1]; }
    short8 bv;
    bv[0] = f2bf(rintf(fminf(7.f, fmaxf(-8.f, w0.x * ia))));
    bv[1] = f2bf(rintf(fminf(7.f, fmaxf(-8.f, w0.y * ia))));
    bv[2] = f2bf(rintf(fminf(7.f, fmaxf(-8.f, w0.z * ia))));
    bv[3] = f2bf(rintf(fminf(7.f, fmaxf(-8.f, w0.w * ia))));
    bv[4] = f2bf(rintf(fminf(7.f, fmaxf(-8.f, w1.x * ia))));
    bv[5] = f2bf(rintf(fminf(7.f, fmaxf(-8.f, w1.y * ia))));
    bv[6] = f2bf(rintf(fminf(7.f, fmaxf(-8.f, w1.z * ia))));
    bv[7] = f2bf(rintf(fminf(7.f, fmaxf(-8.f, w1.w * ia))));
    *(short8*)(dst + (size_t)i * 8) = bv;
    if (has2) {
      short8 cv;
      cv[0] = f2bf(rintf(fminf(7.f, fmaxf(-8.f, w2.x * ia))));
      cv[1] = f2bf(rintf(fminf(7.f, fmaxf(-8.f, w2.y * ia))));
      cv[2] = f2bf(rintf(fminf(7.f, fmaxf(-8.f, w2.z * ia))));
      cv[3] = f2bf(rintf(fminf(7.f, fmaxf(-8.f, w2.w * ia))));
      cv[4] = f2bf(rintf(fminf(7.f, fmaxf(-8.f, w3.x * ia))));
      cv[5] = f2bf(rintf(fminf(7.f, fmaxf(-8.f, w3.y * ia))));
      cv[6] = f2bf(rintf(fminf(7.f, fmaxf(-8.f, w3.z * ia))));
      cv[7] = f2bf(rintf(fminf(7.f, fmaxf(-8.f, w3.w * ia))));
      *(short8*)(dst + (size_t)i1 * 8) = cv;
    }
  }
}

// x:(B,C,48,48) fp32 -> t:(S,B,D) fp32 ; row = s*B+b
__global__ void k_patchify(const float* __restrict__ x, float* __restrict__ t) {
  int i = blockIdx.x * 256 + threadIdx.x;
  if (i >= Mm * Dd) return;
  int d = i % Dd, row = i / Dd;
  int b = row % Bb, s = row / Bb;
  int c = d / 9, r = d % 9;
  int p1 = r / 3, p2 = r % 3;
  int g1 = s / Gg, g2 = s % Gg;
  t[i] = x[((size_t)(b * Cc + c) * IMGi + (g1 * Pp + p1)) * IMGi + (g2 * Pp + p2)];
}

// H:(S,B,D) fp32 -> out:(B,C,48,48) fp32
__global__ void k_unpatch(const float* __restrict__ h, float* __restrict__ out) {
  int i = blockIdx.x * 256 + threadIdx.x;
  if (i >= Bb * Cc * IMGi * IMGi) return;
  int j = i % IMGi, t = i / IMGi;
  int r = t % IMGi; t /= IMGi;
  int c = t % Cc;
  int b = t / Cc;
  int g1 = r / Pp, p1 = r % Pp, g2 = j / Pp, p2 = j % Pp;
  int s = g1 * Gg + g2;
  int d = c * 9 + p1 * 3 + p2;
  out[i] = h[(size_t)(s * Bb + b) * Dd + d];
}

// ---------------- MFMA GEMM: whole-K LDS staging + fused LN(+qe) on A ------
// Block: 256 thr (4 waves), tile 64x64, wave tile 32x32 (4x mfma 16x16x32).
// K multiple of 576. LN fusion valid only when K==576 (all LN-consuming GEMMs).
// A rows: 4 consecutive lanes hold one full row -> stats via 2x shfl_xor.
#define MT 64
#define NT 64
#define KC 576
#define LDKA 584   // A row stride in shorts

// B swizzle: physical byte = row*1152 + (colByte ^ ((row&7)<<4)); involution.
__device__ __forceinline__ int bswz(int row, int colByte) {
  return row * 1152 + (colByte ^ ((row & 7) << 4));
}

__global__ __launch_bounds__(256)
void k_gemm_mfma(const float* __restrict__ Xa, const float* __restrict__ Xb,
                 int n_split, int ldx,
                 const float* __restrict__ qe, const int* __restrict__ qidx,
                 const float* __restrict__ lng, const float* __restrict__ lnb,
                 int ln_on_b,
                 const float* __restrict__ Wraw, const short* __restrict__ Wq,
                 const float* __restrict__ bias, const float* __restrict__ pos,
                 const float* res, int ldr,
                 float* out, int ldo, float* out2,
                 int N, int K,
                 const float* __restrict__ alpha_p, const float* __restrict__ inva_p,
                 int slot, int relu)
{
  __shared__ short As[MT][LDKA];
  __shared__ short Bs[NT * KC];        // swizzled physical image
  const int tid  = threadIdx.x;
  const int wave = tid >> 6, lane = tid & 63;
  const int quad = lane >> 4, l15 = lane & 15;
  const int tile_m = blockIdx.y * MT, tile_n = blockIdx.x * NT;
  const int m_off = (wave >> 1) * 32, n_off = (wave & 1) * 32;
  const int sr = tid >> 2;           // staging row 0..63
  const int sc = (tid & 3) * 8;      // staging col start (shorts), stride 32
  const float inva = inva_p[slot];

  const bool isA = (!Xb || tile_n < n_split);
  const float* X = isA ? Xa : Xb;
  const bool addqe = (qe != nullptr) && isA;
  const bool do_ln = isA ? (lng != nullptr) : (ln_on_b != 0);
  size_t qe_off = 0;
  if (addqe) qe_off = (size_t)qidx[0] * ((size_t)Ss * Dd);

  f32x4 acc00 = {0,0,0,0}, acc01 = {0,0,0,0}, acc10 = {0,0,0,0}, acc11 = {0,0,0,0};

  for (int kc = 0; kc < K; kc += KC) {
    // ---- B: issue 18 async 1KB chunks per wave (72 chunks total) ----
    if (Wq) {
      #pragma unroll
      for (int j = 0; j < 18; ++j) {
        const int c = wave * 18 + j;          // wave-uniform chunk id
        const int p = c * 512 + lane * 8;     // physical short index
        const int prow  = p / KC;
        const int pcolB = (p % KC) * 2;
        const int lcolB = pcolB ^ ((prow & 7) << 4);
        const short* src = Wq + (size_t)(tile_n + prow) * K + kc + (lcolB >> 1);
        gload_lds16(src, (char*)Bs + c * 1024);
      }
    } else {
      const float* wr = Wraw + (size_t)(tile_n + sr) * K + kc;
      #pragma unroll
      for (int j = 0; j < 18; ++j) {
        const int k = sc + j * 32;
        float4 w0 = *(const float4*)(wr + k);
        float4 w1 = *(const float4*)(wr + k + 4);
        short8 bv;
        bv[0] = f2bf(rintf(fminf(7.f, fmaxf(-8.f, w0.x * inva))));
        bv[1] = f2bf(rintf(fminf(7.f, fmaxf(-8.f, w0.y * inva))));
        bv[2] = f2bf(rintf(fminf(7.f, fmaxf(-8.f, w0.z * inva))));
        bv[3] = f2bf(rintf(fminf(7.f, fmaxf(-8.f, w0.w * inva))));
        bv[4] = f2bf(rintf(fminf(7.f, fmaxf(-8.f, w1.x * inva))));
        bv[5] = f2bf(rintf(fminf(7.f, fmaxf(-8.f, w1.y * inva))));
        bv[6] = f2bf(rintf(fminf(7.f, fmaxf(-8.f, w1.z * inva))));
        bv[7] = f2bf(rintf(fminf(7.f, fmaxf(-8.f, w1.w * inva))));
        *(short8*)((char*)Bs + bswz(sr, k * 2)) = bv;
      }
    }

    // ---- A: reg staging fp32 -> bf16, fused LN (+qe) ----
    {
      const int arow = tile_m + sr;
      const float* ar = X + (size_t)arow * ldx + kc;
      float mean = 0.f, sinv = 1.f;
      if (do_ln) {
        float s = 0.f, s2 = 0.f;
        #pragma unroll 6
        for (int j = 0; j < 18; ++j) {
          const int k = sc + j * 32;
          float4 a0 = *(const float4*)(ar + k);
          float4 a1 = *(const float4*)(ar + k + 4);
          s  += (a0.x + a0.y) + (a0.z + a0.w) + (a1.x + a1.y) + (a1.z + a1.w);
          s2 += (a0.x * a0.x + a0.y * a0.y) + (a0.z * a0.z + a0.w * a0.w)
              + (a1.x * a1.x + a1.y * a1.y) + (a1.z * a1.z + a1.w * a1.w);
        }
        s  += __shfl_xor(s, 1);  s  += __shfl_xor(s, 2);
        s2 += __shfl_xor(s2, 1); s2 += __shfl_xor(s2, 2);
        mean = s * (1.f / (float)Dd);
        float var = s2 * (1.f / (float)Dd) - mean * mean;
        sinv = rsqrtf(var + EPSf);
      }
      const float* qr = addqe ? (qe + qe_off + (size_t)(arow >> 2) * Dd + kc) : nullptr;
      #pragma unroll 6
      for (int j = 0; j < 18; ++j) {
        const int k = sc + j * 32;
        float4 a0 = *(const float4*)(ar + k);
        float4 a1 = *(const float4*)(ar + k + 4);
        if (do_ln) {
          float4 g0 = *(const float4*)(lng + kc + k);
          float4 g1 = *(const float4*)(lng + kc + k + 4);
          float4 b0 = *(const float4*)(lnb + kc + k);
          float4 b1 = *(const float4*)(lnb + kc + k + 4);
          a0.x = (a0.x - mean) * sinv * g0.x + b0.x;
          a0.y = (a0.y - mean) * sinv * g0.y + b0.y;
          a0.z = (a0.z - mean) * sinv * g0.z + b0.z;
          a0.w = (a0.w - mean) * sinv * g0.w + b0.w;
          a1.x = (a1.x - mean) * sinv * g1.x + b1.x;
          a1.y = (a1.y - mean) * sinv * g1.y + b1.y;
          a1.z = (a1.z - mean) * sinv * g1.z + b1.z;
          a1.w = (a1.w - mean) * sinv * g1.w + b1.w;
        }
        if (addqe) {
          float4 q0 = *(const float4*)(qr + k);
          float4 q1 = *(const float4*)(qr + k + 4);
          a0.x += q0.x; a0.y += q0.y; a0.z += q0.z; a0.w += q0.w;
          a1.x += q1.x; a1.y += q1.y; a1.z += q1.z; a1.w += q1.w;
        }
        short8 av;
        av[0] = f2bf(a0.x); av[1] = f2bf(a0.y); av[2] = f2bf(a0.z); av[3] = f2bf(a0.w);
        av[4] = f2bf(a1.x); av[5] = f2bf(a1.y); av[6] = f2bf(a1.z); av[7] = f2bf(a1.w);
        *(short8*)&As[sr][k] = av;
      }
    }
    __syncthreads();   // drains vmcnt incl. global_load_lds

    // ---- compute: 18 k-steps, barrier-free ----
    #pragma unroll 3
    for (int ks = 0; ks < KC / 32; ++ks) {
      const int kb = ks * 32 + quad * 8;
      short8 af0 = *(short8*)&As[m_off + l15][kb];
      short8 af1 = *(short8*)&As[m_off + 16 + l15][kb];
      short8 bf0 = *(const short8*)((const char*)Bs + bswz(n_off + l15, kb * 2));
      short8 bf1 = *(const short8*)((const char*)Bs + bswz(n_off + 16 + l15, kb * 2));
      acc00 = __builtin_amdgcn_mfma_f32_16x16x32_bf16(af0, bf0, acc00, 0, 0, 0);
      acc01 = __builtin_amdgcn_mfma_f32_16x16x32_bf16(af0, bf1, acc01, 0, 0, 0);
      acc10 = __builtin_amdgcn_mfma_f32_16x16x32_bf16(af1, bf0, acc10, 0, 0, 0);
      acc11 = __builtin_amdgcn_mfma_f32_16x16x32_bf16(af1, bf1, acc11, 0, 0, 0);
    }
    __syncthreads();
  }

  // ---- epilogue ----
  const float a_s = alpha_p[slot];
  const int rowb = tile_m + m_off + quad * 4;
  const int colb = tile_n + n_off + l15;
  f32x4 accs[4] = {acc00, acc01, acc10, acc11};
  #pragma unroll
  for (int t = 0; t < 4; ++t) {
    int row0 = rowb + ((t >> 1) * 16);
    int col  = colb + ((t & 1) * 16);
    float bv = bias ? bias[col] : 0.f;
    #pragma unroll
    for (int r = 0; r < 4; ++r) {
      int row = row0 + r;
      float v = accs[t][r] * a_s + bv;
      if (res) v += res[(size_t)row * ldr + col];
      if (pos) v += pos[(size_t)(row >> 2) * Dd + col];
      if (relu) v = fmaxf(v, 0.f);
      out[(size_t)row * ldo + col] = v;
      if (out2) out2[(size_t)row * ldo + col] = v;
    }
  }
}

// ---------------- fused flash attention ----------------
// grid: (S/64 q-tiles, B*NH). 256 thr = 4 waves; wave w owns 16 query cols.
__global__ __launch_bounds__(256)
void k_attn(const float* __restrict__ QKV, float* __restrict__ ctx, float scale) {
  __shared__ short Ks[256][72];   // [ki][d]  d 48..63 zero-padded
  __shared__ short Qs[64][72];    // [qi][d]  zero-padded
  __shared__ short Vt[48][264];   // [d][ki]
  __shared__ short Pq[64][264];   // [qi][ki]
  const int qt = blockIdx.x;
  const int b  = blockIdx.y / NHh, h = blockIdx.y % NHh;
  const int tid = threadIdx.x;
  const int w = tid >> 6, lane = tid & 63, quad = lane >> 4, l15 = lane & 15;

  {
    const float* kp = QKV + (size_t)(tid * Bb + b) * 1728 + Dd + h * HDd;
    #pragma unroll
    for (int d0 = 0; d0 < 48; d0 += 4) {
      float4 f = *(const float4*)(kp + d0);
      short4v v = { f2bf(f.x), f2bf(f.y), f2bf(f.z), f2bf(f.w) };
      *(short4v*)&Ks[tid][d0] = v;
    }
    short4v z = {0, 0, 0, 0};
    *(short4v*)&Ks[tid][48] = z; *(short4v*)&Ks[tid][52] = z;
    *(short4v*)&Ks[tid][56] = z; *(short4v*)&Ks[tid][60] = z;
    const float* vp = QKV + (size_t)(tid * Bb + b) * 1728 + 2 * Dd + h * HDd;
    #pragma unroll
    for (int d0 = 0; d0 < 48; d0 += 4) {
      float4 f = *(const float4*)(vp + d0);
      Vt[d0 + 0][tid] = f2bf(f.x);
      Vt[d0 + 1][tid] = f2bf(f.y);
      Vt[d0 + 2][tid] = f2bf(f.z);
      Vt[d0 + 3][tid] = f2bf(f.w);
    }
    if (tid < 64) {
      const float* qp = QKV + (size_t)((qt * 64 + tid) * Bb + b) * 1728 + h * HDd;
      #pragma unroll
      for (int d0 = 0; d0 < 48; d0 += 4) {
        float4 f = *(const float4*)(qp + d0);
        short4v v = { f2bf(f.x), f2bf(f.y), f2bf(f.z), f2bf(f.w) };
        *(short4v*)&Qs[tid][d0] = v;
      }
      *(short4v*)&Qs[tid][48] = z; *(short4v*)&Qs[tid][52] = z;
      *(short4v*)&Qs[tid][56] = z; *(short4v*)&Qs[tid][60] = z;
    }
  }
  __syncthreads();

  short8 bq0 = *(short8*)&Qs[w * 16 + l15][quad * 8];
  short8 bq1 = *(short8*)&Qs[w * 16 + l15][32 + quad * 8];
  f32x4 sf[16];
  #pragma unroll
  for (int mt = 0; mt < 16; ++mt) {
    f32x4 acc = {0, 0, 0, 0};
    short8 a0 = *(short8*)&Ks[mt * 16 + l15][quad * 8];
    short8 a1 = *(short8*)&Ks[mt * 16 + l15][32 + quad * 8];
    acc = __builtin_amdgcn_mfma_f32_16x16x32_bf16(a0, bq0, acc, 0, 0, 0);
    acc = __builtin_amdgcn_mfma_f32_16x16x32_bf16(a1, bq1, acc, 0, 0, 0);
    sf[mt] = acc;
  }

  float mx = -1e30f;
  #pragma unroll
  for (int mt = 0; mt < 16; ++mt)
    #pragma unroll
    for (int r = 0; r < 4; ++r) {
      sf[mt][r] *= scale;
      mx = fmaxf(mx, sf[mt][r]);
    }
  mx = fmaxf(mx, __shfl_xor(mx, 16));
  mx = fmaxf(mx, __shfl_xor(mx, 32));
  float sum = 0.f;
  #pragma unroll
  for (int mt = 0; mt < 16; ++mt)
    #pragma unroll
    for (int r = 0; r < 4; ++r) {
      float e = __expf(sf[mt][r] - mx);
      sf[mt][r] = e;
      sum += e;
    }
  sum += __shfl_xor(sum, 16);
  sum += __shfl_xor(sum, 32);
  float inv = 1.f / sum;

  #pragma unroll
  for (int mt = 0; mt < 16; ++mt) {
    short4v p = { f2bf(sf[mt][0] * inv), f2bf(sf[mt][1] * inv),
                  f2bf(sf[mt][2] * inv), f2bf(sf[mt][3] * inv) };
    *(short4v*)&Pq[w * 16 + l15][mt * 16 + quad * 4] = p;
  }
  __syncthreads();

  f32x4 of0 = {0,0,0,0}, of1 = {0,0,0,0}, of2 = {0,0,0,0};
  #pragma unroll
  for (int kt = 0; kt < 8; ++kt) {
    short8 a = *(short8*)&Pq[w * 16 + l15][kt * 32 + quad * 8];
    short8 b0 = *(short8*)&Vt[l15][kt * 32 + quad * 8];
    short8 b1 = *(short8*)&Vt[16 + l15][kt * 32 + quad * 8];
    short8 b2 = *(short8*)&Vt[32 + l15][kt * 32 + quad * 8];
    of0 = __builtin_amdgcn_mfma_f32_16x16x32_bf16(a, b0, of0, 0, 0, 0);
    of1 = __builtin_amdgcn_mfma_f32_16x16x32_bf16(a, b1, of1, 0, 0, 0);
    of2 = __builtin_amdgcn_mfma_f32_16x16x32_bf16(a, b2, of2, 0, 0, 0);
  }
  const int qg = qt * 64 + w * 16 + quad * 4;
  #pragma unroll
  for (int r = 0; r < 4; ++r) {
    float* cr = ctx + (size_t)((qg + r) * Bb + b) * Dd + h * HDd + l15;
    cr[0]  = of0[r];
    cr[16] = of1[r];
    cr[32] = of2[r];
  }
}

// ---------------- host ----------------

extern "C" void kernel_launch(void* const* d_in, const int* in_sizes, int n_in,
                              void* d_out, int out_size, void* d_ws, size_t ws_size,
                              hipStream_t stream) {
  (void)in_sizes; (void)n_in; (void)out_size;
  const float* x            = (const float*)d_in[0];
  const float* lin_enc_w    = (const float*)d_in[1];
  const float* lin_enc_b    = (const float*)d_in[2];
  const float* pos_emb      = (const float*)d_in[3];
  const float* query_embed  = (const float*)d_in[4];
  const float* enc_in_w     = (const float*)d_in[5];
  const float* enc_out_w    = (const float*)d_in[6];
  const float* enc_l1_w     = (const float*)d_in[7];
  const float* enc_l1_b     = (const float*)d_in[8];
  const float* enc_l2_w     = (const float*)d_in[9];
  const float* enc_l2_b     = (const float*)d_in[10];
  const float* enc_ln1_g    = (const float*)d_in[11];
  const float* enc_ln1_b    = (const float*)d_in[12];
  const float* enc_ln2_g    = (const float*)d_in[13];
  const float* enc_ln2_b    = (const float*)d_in[14];
  const float* dec_sa_in_w  = (const float*)d_in[15];
  const float* dec_sa_out_w = (const float*)d_in[16];
  const float* dec_ca_in_w  = (const float*)d_in[17];
  const float* dec_ca_out_w = (const float*)d_in[18];
  const float* dec_l1_w     = (const float*)d_in[19];
  const float* dec_l1_b     = (const float*)d_in[20];
  const float* dec_l2_w     = (const float*)d_in[21];
  const float* dec_l2_b     = (const float*)d_in[22];
  const float* dec_ln1_g    = (const float*)d_in[23];
  const float* dec_ln1_b    = (const float*)d_in[24];
  const float* dec_ln2_g    = (const float*)d_in[25];
  const float* dec_ln2_b    = (const float*)d_in[26];
  const float* dec_ln3_g    = (const float*)d_in[27];
  const float* dec_ln3_b    = (const float*)d_in[28];
  const float* head1_w      = (const float*)d_in[29];
  const float* head1_b      = (const float*)d_in[30];
  const float* head2_w      = (const float*)d_in[31];
  const float* head2_b      = (const float*)d_in[32];
  const int*   query_idx    = (const int*)d_in[33];
  float* out = (float*)d_out;

  const int DD  = Dd * Dd;
  const int IN3 = 3 * Dd * Dd;
  const int FF  = HIDh * Dd;
  const int MD  = Mm * Dd;

  float* ws = (float*)d_ws;
  float* ABSUM = ws;
  float* ALPHA = ws + 64;
  float* INVA  = ws + 128;
  float* H   = ws + 256;
  float* MEM = H   + MD;
  float* LN  = MEM + MD;
  float* LNQ = LN  + MD;   // retained in layout (unused)
  float* CTX = LNQ + MD;
  float* QKV = CTX + MD;
  size_t act_floats = 256 + 5 * (size_t)MD + (size_t)Mm * HIDh;
  short* WQ = (short*)(ws + act_floats);
  const size_t WQ_ELEMS = (size_t)DD + 4 * ((size_t)IN3 + DD + FF + FF)
                        + 4 * ((size_t)IN3 + DD + IN3 + DD + FF + FF)
                        + 2 * (size_t)FF;
  const bool use_wq = ws_size >= act_floats * 4 + WQ_ELEMS * 2;

  QJobs jobs;
  int j = 0; int off = 0;
  auto addjob = [&](const float* p, int n) { jobs.ptr[j] = p; jobs.n[j] = n; jobs.off[j] = off; off += n; j++; };
  addjob(lin_enc_w, DD);
  for (int l = 0; l < NLl; ++l) addjob(enc_in_w  + (size_t)l * IN3, IN3);
  for (int l = 0; l < NLl; ++l) addjob(enc_out_w + (size_t)l * DD,  DD);
  for (int l = 0; l < NLl; ++l) addjob(enc_l1_w  + (size_t)l * FF,  FF);
  for (int l = 0; l < NLl; ++l) addjob(enc_l2_w  + (size_t)l * FF,  FF);
  for (int l = 0; l < NLl; ++l) addjob(dec_sa_in_w  + (size_t)l * IN3, IN3);
  for (int l = 0; l < NLl; ++l) addjob(dec_sa_out_w + (size_t)l * DD,  DD);
  for (int l = 0; l < NLl; ++l) addjob(dec_ca_in_w  + (size_t)l * IN3, IN3);
  for (int l = 0; l < NLl; ++l) addjob(dec_ca_out_w + (size_t)l * DD,  DD);
  for (int l = 0; l < NLl; ++l) addjob(dec_l1_w + (size_t)l * FF, FF);
  for (int l = 0; l < NLl; ++l) addjob(dec_l2_w + (size_t)l * FF, FF);
  addjob(head1_w, FF);
  addjob(head2_w, FF);

  k_zero<<<1, 64, 0, stream>>>(ABSUM, 64);
  k_abssum<<<NJOBS * 64, 256, 0, stream>>>(jobs, ABSUM);
  k_alpha<<<1, 64, 0, stream>>>(jobs, ABSUM, ALPHA, INVA);
  if (use_wq) k_quant<<<NJOBS * 128, 256, 0, stream>>>(jobs, INVA, WQ);

  // gemm(Xa, Xb, n_split, ldx, qe, lng, lnb, lnB, W, slot, bias, pos, res, ldr,
  //      o, ldo, o2, N, K, relu)
  auto gemm = [&](const float* Xa, const float* Xb, int n_split, int ldx,
                  const float* qe, const float* lng, const float* lnb, int lnB,
                  const float* W, int slot, const float* bias, const float* pos,
                  const float* res, int ldr,
                  float* o, int ldo, float* o2, int N, int K, int relu) {
    dim3 grid(N / NT, Mm / MT);
    const short* wq = use_wq ? WQ + (size_t)jobs.off[slot] : nullptr;
    const float* wr = use_wq ? nullptr : W;
    k_gemm_mfma<<<grid, 256, 0, stream>>>(Xa, Xb, n_split, ldx, qe, query_idx,
                                          lng, lnb, lnB,
                                          wr, wq, bias, pos, res, ldr,
                                          o, ldo, o2, N, K, ALPHA, INVA, slot, relu);
  };

  const float scale = 1.f / sqrtf((float)HDd);
  auto attn = [&](const float* out_w, int out_slot) {
    k_attn<<<dim3(Ss / 64, Bb * NHh), 256, 0, stream>>>(QKV, CTX, scale);
    gemm(CTX, nullptr, 0, Dd, nullptr, nullptr, nullptr, 0, out_w, out_slot,
         nullptr, nullptr, H, Dd, H, Dd, nullptr, Dd, Dd, 0);
  };

  const int NELEM = Mm * Dd;
  const int EB = (NELEM + 255) / 256;

  // ---- stem: t = qlinear(t)+t, then +pos fused in epilogue ----
  k_patchify<<<EB, 256, 0, stream>>>(x, LN);
  gemm(LN, nullptr, 0, Dd, nullptr, nullptr, nullptr, 0, lin_enc_w, 0,
       lin_enc_b, pos_emb, LN, Dd, H, Dd, nullptr, Dd, Dd, 0);

  // ---- encoder (LN fused into GEMM A-staging) ----
  for (int l = 0; l < NLl; ++l) {
    gemm(H, nullptr, 0, Dd, nullptr, enc_ln1_g + l * Dd, enc_ln1_b + l * Dd, 0,
         enc_in_w + (size_t)l * IN3, 1 + l,
         nullptr, nullptr, nullptr, 0, QKV, 1728, nullptr, 1728, Dd, 0);
    attn(enc_out_w + (size_t)l * DD, 5 + l);
    gemm(H, nullptr, 0, Dd, nullptr, enc_ln2_g + l * Dd, enc_ln2_b + l * Dd, 0,
         enc_l1_w + (size_t)l * FF, 9 + l,
         enc_l1_b + l * HIDh, nullptr, nullptr, 0, QKV, HIDh, nullptr, HIDh, Dd, 1);
    // last encoder FF2 also writes MEM (fused H->MEM copy)
    gemm(QKV, nullptr, 0, HIDh, nullptr, nullptr, nullptr, 0,
         enc_l2_w + (size_t)l * FF, 13 + l,
         enc_l2_b + l * Dd, nullptr, H, Dd, H, Dd, (l == NLl - 1) ? MEM : nullptr,
         Dd, HIDh, 0);
  }

  // ---- decoder (LN + qe fused into GEMM A-staging) ----
  for (int l = 0; l < NLl; ++l) {
    // merged SA-in: cols [0,1152) A=LN(H)+qe (Q,K), cols [1152,1728) A=LN(H) (V)
    gemm(H, H, 2 * Dd, Dd, query_embed,
         dec_ln1_g + l * Dd, dec_ln1_b + l * Dd, 1,
         dec_sa_in_w + (size_t)l * IN3, 17 + l,
         nullptr, nullptr, nullptr, 0, QKV, 1728, nullptr, 1728, Dd, 0);
    attn(dec_sa_out_w + (size_t)l * DD, 21 + l);
    // merged CA-in: cols [0,576) A=LN(H)+qe (Q), cols [576,1728) A=MEM raw (K,V)
    gemm(H, MEM, Dd, Dd, query_embed,
         dec_ln2_g + l * Dd, dec_ln2_b + l * Dd, 0,
         dec_ca_in_w + (size_t)l * IN3, 25 + l,
         nullptr, nullptr, nullptr, 0, QKV, 1728, nullptr, 1728, Dd, 0);
    attn(dec_ca_out_w + (size_t)l * DD, 29 + l);
    gemm(H, nullptr, 0, Dd, nullptr, dec_ln3_g + l * Dd, dec_ln3_b + l * Dd, 0,
         dec_l1_w + (size_t)l * FF, 33 + l,
         dec_l1_b + l * HIDh, nullptr, nullptr, 0, QKV, HIDh, nullptr, HIDh, Dd, 1);
    gemm(QKV, nullptr, 0, HIDh, nullptr, nullptr, nullptr, 0,
         dec_l2_w + (size_t)l * FF, 37 + l,
         dec_l2_b + l * Dd, nullptr, H, Dd, H, Dd, nullptr, Dd, HIDh, 0);
  }

  // ---- head (no LN in reference) ----
  gemm(H, nullptr, 0, Dd, nullptr, nullptr, nullptr, 0, head1_w, 41,
       head1_b, nullptr, nullptr, 0, QKV, HIDh, nullptr, HIDh, Dd, 1);
  gemm(QKV, nullptr, 0, HIDh, nullptr, nullptr, nullptr, 0, head2_w, 42,
       head2_b, nullptr, H, Dd, H, Dd, nullptr, Dd, HIDh, 0);

  // ---- output ----
  k_unpatch<<<EB, 256, 0, stream>>>(H, out);
}

// Round 6
// 1531.066 us; speedup vs baseline: 1.1407x; 1.1407x over previous
//
#include <hip/hip_runtime.h>
#include <cstddef>

#define Pp    3
#define Cc    64
#define IMGi  48
#define Gg    16
#define Dd    576
#define NHh   12
#define HDd   48
#define HIDh  2304
#define NLl   4
#define Ss    256
#define Bb    4
#define Mm    1024          // S*B tokens
#define EPSf  1e-5f
#define NJOBS 43
#define NSTAT 20            // per-site LN stat tables (sum, sumsq) per row

typedef short short8 __attribute__((ext_vector_type(8)));
typedef short short4v __attribute__((ext_vector_type(4)));
typedef float f32x4  __attribute__((ext_vector_type(4)));

struct QJobs { const float* ptr[NJOBS]; int n[NJOBS]; int off[NJOBS]; };

// float -> bf16 (RNE), bit-level
__device__ __forceinline__ short f2bf(float f) {
  unsigned u = __float_as_uint(f);
  u = u + 0x7fffu + ((u >> 16) & 1u);
  return (short)(u >> 16);
}

// async global->LDS, 16B per lane. dst must be wave-uniform; HW adds lane*16.
typedef __attribute__((address_space(3))) unsigned lds_u32;
typedef __attribute__((address_space(1))) const unsigned glob_u32;
__device__ __forceinline__ void gload_lds16(const void* g, void* l) {
  __builtin_amdgcn_global_load_lds((glob_u32*)g, (lds_u32*)l, 16, 0, 0);
}

// ---------------- small utility kernels ----------------

__global__ void k_zero(float* p, int n) {
  int i = blockIdx.x * blockDim.x + threadIdx.x;
  if (i < n) p[i] = 0.f;
}

__global__ void k_abssum(QJobs jobs, float* absum) {
  int job = blockIdx.x >> 6, blk = blockIdx.x & 63;
  const float4* p4 = (const float4*)jobs.ptr[job];
  int n4 = jobs.n[job] >> 2;
  float s0 = 0.f, s1 = 0.f, s2 = 0.f, s3 = 0.f;
  for (int i = blk * 1024 + threadIdx.x; i < n4; i += 64 * 1024) {
    float4 v = p4[i];
    s0 += fabsf(v.x) + fabsf(v.y) + fabsf(v.z) + fabsf(v.w);
    int i1 = i + 256;
    if (i1 < n4) { float4 w = p4[i1]; s1 += fabsf(w.x) + fabsf(w.y) + fabsf(w.z) + fabsf(w.w); }
    int i2 = i + 512;
    if (i2 < n4) { float4 w = p4[i2]; s2 += fabsf(w.x) + fabsf(w.y) + fabsf(w.z) + fabsf(w.w); }
    int i3 = i + 768;
    if (i3 < n4) { float4 w = p4[i3]; s3 += fabsf(w.x) + fabsf(w.y) + fabsf(w.z) + fabsf(w.w); }
  }
  float s = (s0 + s1) + (s2 + s3);
  #pragma unroll
  for (int o = 32; o; o >>= 1) s += __shfl_xor(s, o);
  __shared__ float red[4];
  if ((threadIdx.x & 63) == 0) red[threadIdx.x >> 6] = s;
  __syncthreads();
  if (threadIdx.x == 0) atomicAdd(&absum[job], (red[0] + red[1]) + (red[2] + red[3]));
}

__global__ void k_alpha(QJobs jobs, const float* absum, float* alpha, float* inva) {
  int j = threadIdx.x;
  if (j < NJOBS) {
    float a = 2.f * (absum[j] / (float)jobs.n[j]) / sqrtf(7.f);
    alpha[j] = a;
    inva[j] = 1.f / a;
  }
}

// pre-quantize all weights: wq = bf16( rint(clamp(w/alpha,-8,7)) )
__global__ void k_quant(QJobs jobs, const float* __restrict__ inva, short* __restrict__ wq) {
  int job = blockIdx.x >> 7, blk = blockIdx.x & 127;
  const float* p = jobs.ptr[job];
  int n8 = jobs.n[job] >> 3;
  short* dst = wq + (size_t)jobs.off[job];
  float ia = inva[job];
  for (int i = blk * 512 + threadIdx.x; i < n8; i += 128 * 512) {
    const float4* p4 = (const float4*)(p + (size_t)i * 8);
    float4 w0 = p4[0], w1 = p4[1];
    int i1 = i + 256;
    float4 w2, w3;
    bool has2 = i1 < n8;
    if (has2) { const float4* q4 = (const float4*)(p + (size_t)i1 * 8); w2 = q4[0]; w3 = q4[1]; }
    short8 bv;
    bv[0] = f2bf(rintf(fminf(7.f, fmaxf(-8.f, w0.x * ia))));
    bv[1] = f2bf(rintf(fminf(7.f, fmaxf(-8.f, w0.y * ia))));
    bv[2] = f2bf(rintf(fminf(7.f, fmaxf(-8.f, w0.z * ia))));
    bv[3] = f2bf(rintf(fminf(7.f, fmaxf(-8.f, w0.w * ia))));
    bv[4] = f2bf(rintf(fminf(7.f, fmaxf(-8.f, w1.x * ia))));
    bv[5] = f2bf(rintf(fminf(7.f, fmaxf(-8.f, w1.y * ia))));
    bv[6] = f2bf(rintf(fminf(7.f, fmaxf(-8.f, w1.z * ia))));
    bv[7] = f2bf(rintf(fminf(7.f, fmaxf(-8.f, w1.w * ia))));
    *(short8*)(dst + (size_t)i * 8) = bv;
    if (has2) {
      short8 cv;
      cv[0] = f2bf(rintf(fminf(7.f, fmaxf(-8.f, w2.x * ia))));
      cv[1] = f2bf(rintf(fminf(7.f, fmaxf(-8.f, w2.y * ia))));
      cv[2] = f2bf(rintf(fminf(7.f, fmaxf(-8.f, w2.z * ia))));
      cv[3] = f2bf(rintf(fminf(7.f, fmaxf(-8.f, w2.w * ia))));
      cv[4] = f2bf(rintf(fminf(7.f, fmaxf(-8.f, w3.x * ia))));
      cv[5] = f2bf(rintf(fminf(7.f, fmaxf(-8.f, w3.y * ia))));
      cv[6] = f2bf(rintf(fminf(7.f, fmaxf(-8.f, w3.z * ia))));
      cv[7] = f2bf(rintf(fminf(7.f, fmaxf(-8.f, w3.w * ia))));
      *(short8*)(dst + (size_t)i1 * 8) = cv;
    }
  }
}

// x:(B,C,48,48) fp32 -> t:(S,B,D) fp32 ; row = s*B+b
__global__ void k_patchify(const float* __restrict__ x, float* __restrict__ t) {
  int i = blockIdx.x * 256 + threadIdx.x;
  if (i >= Mm * Dd) return;
  int d = i % Dd, row = i / Dd;
  int b = row % Bb, s = row / Bb;
  int c = d / 9, r = d % 9;
  int p1 = r / 3, p2 = r % 3;
  int g1 = s / Gg, g2 = s % Gg;
  t[i] = x[((size_t)(b * Cc + c) * IMGi + (g1 * Pp + p1)) * IMGi + (g2 * Pp + p2)];
}

// H:(S,B,D) fp32 -> out:(B,C,48,48) fp32
__global__ void k_unpatch(const float* __restrict__ h, float* __restrict__ out) {
  int i = blockIdx.x * 256 + threadIdx.x;
  if (i >= Bb * Cc * IMGi * IMGi) return;
  int j = i % IMGi, t = i / IMGi;
  int r = t % IMGi; t /= IMGi;
  int c = t % Cc;
  int b = t / Cc;
  int g1 = r / Pp, p1 = r % Pp, g2 = j / Pp, p2 = j % Pp;
  int s = g1 * Gg + g2;
  int d = c * 9 + p1 * 3 + p2;
  out[i] = h[(size_t)(s * Bb + b) * Dd + d];
}

// ---------------- MFMA GEMM ------------------------------------------------
// Block: 256 thr (4 waves), tile 64x64, wave tile 32x32 (4x mfma 16x16x32).
// K multiple of 288 (576 or 2304). LDS 75.9 KB -> 2 blocks/CU.
// B LDS layout: padded stride 304 shorts (608B): row rotation covers row%4;
// XOR swizzle ((row>>2)&3)<<4 covers row/4%4 -> 2-way bank aliasing (free).
// Mask < 64 stays inside the 608B padded row: no cross-row escape (R5 bug).
// LN applied in-staging via per-row (sum,sumsq) tables filled by producer
// GEMM epilogues (statOut, atomics); consumer passes statA/statB.
#define MT 64
#define NT 64
#define KC 288
#define LDKA 296   // A row stride in shorts
#define LDKB 304   // B row stride in shorts (608 B)
#define BCHUNKS 38 // 64*304 shorts / 512 shorts-per-1KB-chunk

__device__ __forceinline__ int bswz(int row, int colByte) {
  return row * (LDKB * 2) + (colByte ^ (((row >> 2) & 3) << 4));
}

__global__ __launch_bounds__(256)
void k_gemm_mfma(const float* __restrict__ Xa, const float* __restrict__ Xb,
                 int n_split, int ldx,
                 const float* __restrict__ qe, const int* __restrict__ qidx,
                 const float* __restrict__ lng, const float* __restrict__ lnb,
                 const float* __restrict__ statA, const float* __restrict__ statB,
                 const float* __restrict__ Wraw, const short* __restrict__ Wq,
                 const float* __restrict__ bias, const float* __restrict__ pos,
                 const float* res, int ldr,
                 float* out, int ldo, float* out2, float* statOut,
                 int N, int K,
                 const float* __restrict__ alpha_p, const float* __restrict__ inva_p,
                 int slot, int relu)
{
  __shared__ short As[MT][LDKA];
  __shared__ short Bs[NT * LDKB];      // swizzled padded image (38 KB)
  const int tid  = threadIdx.x;
  const int wave = tid >> 6, lane = tid & 63;
  const int quad = lane >> 4, l15 = lane & 15;
  const int tile_m = blockIdx.y * MT, tile_n = blockIdx.x * NT;
  const int m_off = (wave >> 1) * 32, n_off = (wave & 1) * 32;
  const int sr = tid >> 2;           // staging row 0..63
  const int sc = (tid & 3) * 8;      // staging col start (shorts), stride 32
  const float inva = inva_p[slot];

  const bool isA = (!Xb || tile_n < n_split);
  const float* X = isA ? Xa : Xb;
  const bool addqe = (qe != nullptr) && isA;
  const float* stat = isA ? statA : statB;
  size_t qe_off = 0;
  if (addqe) qe_off = (size_t)qidx[0] * ((size_t)Ss * Dd);

  // per-row LN params from stat table (single read per staging thread)
  float mean = 0.f, sinv = 1.f;
  if (stat) {
    float2 st = *(const float2*)&stat[2 * (tile_m + sr)];
    mean = st.x * (1.f / (float)Dd);
    float var = st.y * (1.f / (float)Dd) - mean * mean;
    sinv = rsqrtf(var + EPSf);
  }

  f32x4 acc00 = {0,0,0,0}, acc01 = {0,0,0,0}, acc10 = {0,0,0,0}, acc11 = {0,0,0,0};

  for (int kc = 0; kc < K; kc += KC) {
    // ---- B: async 1KB chunks into padded+swizzled image ----
    if (Wq) {
      #pragma unroll
      for (int j = 0; j < 10; ++j) {
        const int c = wave * 10 + j;          // wave-uniform chunk id
        if (c < BCHUNKS) {
          const int p = c * 512 + lane * 8;   // physical short index
          const int prow = p / LDKB;
          const int pcolB = (p % LDKB) * 2;   // physical byte col in [0,608)
          const int lcolB = pcolB ^ (((prow >> 2) & 3) << 4);
          // pad slots whose inverse-swizzle falls outside the logical row are
          // never read: clamp their source in-bounds.
          const short* src = (lcolB < 576)
            ? Wq + (size_t)(tile_n + prow) * K + kc + (lcolB >> 1)
            : Wq;
          gload_lds16(src, (char*)Bs + c * 1024);
        }
      }
    } else {
      const float* wr = Wraw + (size_t)(tile_n + sr) * K + kc;
      #pragma unroll
      for (int j = 0; j < 9; ++j) {
        const int k = sc + j * 32;
        float4 w0 = *(const float4*)(wr + k);
        float4 w1 = *(const float4*)(wr + k + 4);
        short8 bv;
        bv[0] = f2bf(rintf(fminf(7.f, fmaxf(-8.f, w0.x * inva))));
        bv[1] = f2bf(rintf(fminf(7.f, fmaxf(-8.f, w0.y * inva))));
        bv[2] = f2bf(rintf(fminf(7.f, fmaxf(-8.f, w0.z * inva))));
        bv[3] = f2bf(rintf(fminf(7.f, fmaxf(-8.f, w0.w * inva))));
        bv[4] = f2bf(rintf(fminf(7.f, fmaxf(-8.f, w1.x * inva))));
        bv[5] = f2bf(rintf(fminf(7.f, fmaxf(-8.f, w1.y * inva))));
        bv[6] = f2bf(rintf(fminf(7.f, fmaxf(-8.f, w1.z * inva))));
        bv[7] = f2bf(rintf(fminf(7.f, fmaxf(-8.f, w1.w * inva))));
        *(short8*)((char*)Bs + bswz(sr, k * 2)) = bv;
      }
    }

    // ---- A: single-pass reg staging fp32 -> bf16, LN (+qe) applied inline ----
    {
      const int arow = tile_m + sr;
      const float* ar = X + (size_t)arow * ldx + kc;
      const float* qr = addqe ? (qe + qe_off + (size_t)(arow >> 2) * Dd + kc) : nullptr;
      #pragma unroll
      for (int j = 0; j < 9; ++j) {
        const int k = sc + j * 32;
        float4 a0 = *(const float4*)(ar + k);
        float4 a1 = *(const float4*)(ar + k + 4);
        if (stat) {
          float4 g0 = *(const float4*)(lng + kc + k);
          float4 g1 = *(const float4*)(lng + kc + k + 4);
          float4 b0 = *(const float4*)(lnb + kc + k);
          float4 b1 = *(const float4*)(lnb + kc + k + 4);
          a0.x = (a0.x - mean) * sinv * g0.x + b0.x;
          a0.y = (a0.y - mean) * sinv * g0.y + b0.y;
          a0.z = (a0.z - mean) * sinv * g0.z + b0.z;
          a0.w = (a0.w - mean) * sinv * g0.w + b0.w;
          a1.x = (a1.x - mean) * sinv * g1.x + b1.x;
          a1.y = (a1.y - mean) * sinv * g1.y + b1.y;
          a1.z = (a1.z - mean) * sinv * g1.z + b1.z;
          a1.w = (a1.w - mean) * sinv * g1.w + b1.w;
        }
        if (addqe) {
          float4 q0 = *(const float4*)(qr + k);
          float4 q1 = *(const float4*)(qr + k + 4);
          a0.x += q0.x; a0.y += q0.y; a0.z += q0.z; a0.w += q0.w;
          a1.x += q1.x; a1.y += q1.y; a1.z += q1.z; a1.w += q1.w;
        }
        short8 av;
        av[0] = f2bf(a0.x); av[1] = f2bf(a0.y); av[2] = f2bf(a0.z); av[3] = f2bf(a0.w);
        av[4] = f2bf(a1.x); av[5] = f2bf(a1.y); av[6] = f2bf(a1.z); av[7] = f2bf(a1.w);
        *(short8*)&As[sr][k] = av;
      }
    }
    __syncthreads();   // drains vmcnt incl. global_load_lds

    // ---- compute: 9 k-steps, barrier-free ----
    #pragma unroll 3
    for (int ks = 0; ks < KC / 32; ++ks) {
      const int kb = ks * 32 + quad * 8;
      short8 af0 = *(short8*)&As[m_off + l15][kb];
      short8 af1 = *(short8*)&As[m_off + 16 + l15][kb];
      short8 bf0 = *(const short8*)((const char*)Bs + bswz(n_off + l15, kb * 2));
      short8 bf1 = *(const short8*)((const char*)Bs + bswz(n_off + 16 + l15, kb * 2));
      acc00 = __builtin_amdgcn_mfma_f32_16x16x32_bf16(af0, bf0, acc00, 0, 0, 0);
      acc01 = __builtin_amdgcn_mfma_f32_16x16x32_bf16(af0, bf1, acc01, 0, 0, 0);
      acc10 = __builtin_amdgcn_mfma_f32_16x16x32_bf16(af1, bf0, acc10, 0, 0, 0);
      acc11 = __builtin_amdgcn_mfma_f32_16x16x32_bf16(af1, bf1, acc11, 0, 0, 0);
    }
    __syncthreads();
  }

  // ---- epilogue ----
  const float a_s = alpha_p[slot];
  const int rowb = tile_m + m_off + quad * 4;
  const int colb = tile_n + n_off + l15;
  f32x4 accs[4] = {acc00, acc01, acc10, acc11};
  float vsum[2][4], vsq[2][4];
  #pragma unroll
  for (int rt = 0; rt < 2; ++rt)
    #pragma unroll
    for (int r = 0; r < 4; ++r) { vsum[rt][r] = 0.f; vsq[rt][r] = 0.f; }

  #pragma unroll
  for (int t = 0; t < 4; ++t) {
    int row0 = rowb + ((t >> 1) * 16);
    int col  = colb + ((t & 1) * 16);
    float bv = bias ? bias[col] : 0.f;
    #pragma unroll
    for (int r = 0; r < 4; ++r) {
      int row = row0 + r;
      float v = accs[t][r] * a_s + bv;
      if (res) v += res[(size_t)row * ldr + col];
      if (pos) v += pos[(size_t)(row >> 2) * Dd + col];
      if (relu) v = fmaxf(v, 0.f);
      out[(size_t)row * ldo + col] = v;
      if (out2) out2[(size_t)row * ldo + col] = v;
      vsum[t >> 1][r] += v;
      vsq[t >> 1][r]  += v * v;
    }
  }

  // ---- per-row LN-stat accumulation for downstream consumers ----
  if (statOut) {
    #pragma unroll
    for (int rt = 0; rt < 2; ++rt) {
      #pragma unroll
      for (int r = 0; r < 4; ++r) {
        float s = vsum[rt][r], q = vsq[rt][r];
        #pragma unroll
        for (int o = 1; o < 16; o <<= 1) {
          s += __shfl_xor(s, o);
          q += __shfl_xor(q, o);
        }
        if (l15 == 0) {
          int row = rowb + rt * 16 + r;
          atomicAdd(&statOut[2 * row],     s);
          atomicAdd(&statOut[2 * row + 1], q);
        }
      }
    }
  }
}

// ---------------- fused flash attention ----------------
__global__ __launch_bounds__(256)
void k_attn(const float* __restrict__ QKV, float* __restrict__ ctx, float scale) {
  __shared__ short Ks[256][72];   // [ki][d]  d 48..63 zero-padded
  __shared__ short Qs[64][72];    // [qi][d]  zero-padded
  __shared__ short Vt[48][264];   // [d][ki]
  __shared__ short Pq[64][264];   // [qi][ki]
  const int qt = blockIdx.x;
  const int b  = blockIdx.y / NHh, h = blockIdx.y % NHh;
  const int tid = threadIdx.x;
  const int w = tid >> 6, lane = tid & 63, quad = lane >> 4, l15 = lane & 15;

  {
    const float* kp = QKV + (size_t)(tid * Bb + b) * 1728 + Dd + h * HDd;
    #pragma unroll
    for (int d0 = 0; d0 < 48; d0 += 4) {
      float4 f = *(const float4*)(kp + d0);
      short4v v = { f2bf(f.x), f2bf(f.y), f2bf(f.z), f2bf(f.w) };
      *(short4v*)&Ks[tid][d0] = v;
    }
    short4v z = {0, 0, 0, 0};
    *(short4v*)&Ks[tid][48] = z; *(short4v*)&Ks[tid][52] = z;
    *(short4v*)&Ks[tid][56] = z; *(short4v*)&Ks[tid][60] = z;
    const float* vp = QKV + (size_t)(tid * Bb + b) * 1728 + 2 * Dd + h * HDd;
    #pragma unroll
    for (int d0 = 0; d0 < 48; d0 += 4) {
      float4 f = *(const float4*)(vp + d0);
      Vt[d0 + 0][tid] = f2bf(f.x);
      Vt[d0 + 1][tid] = f2bf(f.y);
      Vt[d0 + 2][tid] = f2bf(f.z);
      Vt[d0 + 3][tid] = f2bf(f.w);
    }
    if (tid < 64) {
      const float* qp = QKV + (size_t)((qt * 64 + tid) * Bb + b) * 1728 + h * HDd;
      #pragma unroll
      for (int d0 = 0; d0 < 48; d0 += 4) {
        float4 f = *(const float4*)(qp + d0);
        short4v v = { f2bf(f.x), f2bf(f.y), f2bf(f.z), f2bf(f.w) };
        *(short4v*)&Qs[tid][d0] = v;
      }
      *(short4v*)&Qs[tid][48] = z; *(short4v*)&Qs[tid][52] = z;
      *(short4v*)&Qs[tid][56] = z; *(short4v*)&Qs[tid][60] = z;
    }
  }
  __syncthreads();

  short8 bq0 = *(short8*)&Qs[w * 16 + l15][quad * 8];
  short8 bq1 = *(short8*)&Qs[w * 16 + l15][32 + quad * 8];
  f32x4 sf[16];
  #pragma unroll
  for (int mt = 0; mt < 16; ++mt) {
    f32x4 acc = {0, 0, 0, 0};
    short8 a0 = *(short8*)&Ks[mt * 16 + l15][quad * 8];
    short8 a1 = *(short8*)&Ks[mt * 16 + l15][32 + quad * 8];
    acc = __builtin_amdgcn_mfma_f32_16x16x32_bf16(a0, bq0, acc, 0, 0, 0);
    acc = __builtin_amdgcn_mfma_f32_16x16x32_bf16(a1, bq1, acc, 0, 0, 0);
    sf[mt] = acc;
  }

  float mx = -1e30f;
  #pragma unroll
  for (int mt = 0; mt < 16; ++mt)
    #pragma unroll
    for (int r = 0; r < 4; ++r) {
      sf[mt][r] *= scale;
      mx = fmaxf(mx, sf[mt][r]);
    }
  mx = fmaxf(mx, __shfl_xor(mx, 16));
  mx = fmaxf(mx, __shfl_xor(mx, 32));
  float sum = 0.f;
  #pragma unroll
  for (int mt = 0; mt < 16; ++mt)
    #pragma unroll
    for (int r = 0; r < 4; ++r) {
      float e = __expf(sf[mt][r] - mx);
      sf[mt][r] = e;
      sum += e;
    }
  sum += __shfl_xor(sum, 16);
  sum += __shfl_xor(sum, 32);
  float inv = 1.f / sum;

  #pragma unroll
  for (int mt = 0; mt < 16; ++mt) {
    short4v p = { f2bf(sf[mt][0] * inv), f2bf(sf[mt][1] * inv),
                  f2bf(sf[mt][2] * inv), f2bf(sf[mt][3] * inv) };
    *(short4v*)&Pq[w * 16 + l15][mt * 16 + quad * 4] = p;
  }
  __syncthreads();

  f32x4 of0 = {0,0,0,0}, of1 = {0,0,0,0}, of2 = {0,0,0,0};
  #pragma unroll
  for (int kt = 0; kt < 8; ++kt) {
    short8 a = *(short8*)&Pq[w * 16 + l15][kt * 32 + quad * 8];
    short8 b0 = *(short8*)&Vt[l15][kt * 32 + quad * 8];
    short8 b1 = *(short8*)&Vt[16 + l15][kt * 32 + quad * 8];
    short8 b2 = *(short8*)&Vt[32 + l15][kt * 32 + quad * 8];
    of0 = __builtin_amdgcn_mfma_f32_16x16x32_bf16(a, b0, of0, 0, 0, 0);
    of1 = __builtin_amdgcn_mfma_f32_16x16x32_bf16(a, b1, of1, 0, 0, 0);
    of2 = __builtin_amdgcn_mfma_f32_16x16x32_bf16(a, b2, of2, 0, 0, 0);
  }
  const int qg = qt * 64 + w * 16 + quad * 4;
  #pragma unroll
  for (int r = 0; r < 4; ++r) {
    float* cr = ctx + (size_t)((qg + r) * Bb + b) * Dd + h * HDd + l15;
    cr[0]  = of0[r];
    cr[16] = of1[r];
    cr[32] = of2[r];
  }
}

// ---------------- host ----------------

extern "C" void kernel_launch(void* const* d_in, const int* in_sizes, int n_in,
                              void* d_out, int out_size, void* d_ws, size_t ws_size,
                              hipStream_t stream) {
  (void)in_sizes; (void)n_in; (void)out_size;
  const float* x            = (const float*)d_in[0];
  const float* lin_enc_w    = (const float*)d_in[1];
  const float* lin_enc_b    = (const float*)d_in[2];
  const float* pos_emb      = (const float*)d_in[3];
  const float* query_embed  = (const float*)d_in[4];
  const float* enc_in_w     = (const float*)d_in[5];
  const float* enc_out_w    = (const float*)d_in[6];
  const float* enc_l1_w     = (const float*)d_in[7];
  const float* enc_l1_b     = (const float*)d_in[8];
  const float* enc_l2_w     = (const float*)d_in[9];
  const float* enc_l2_b     = (const float*)d_in[10];
  const float* enc_ln1_g    = (const float*)d_in[11];
  const float* enc_ln1_b    = (const float*)d_in[12];
  const float* enc_ln2_g    = (const float*)d_in[13];
  const float* enc_ln2_b    = (const float*)d_in[14];
  const float* dec_sa_in_w  = (const float*)d_in[15];
  const float* dec_sa_out_w = (const float*)d_in[16];
  const float* dec_ca_in_w  = (const float*)d_in[17];
  const float* dec_ca_out_w = (const float*)d_in[18];
  const float* dec_l1_w     = (const float*)d_in[19];
  const float* dec_l1_b     = (const float*)d_in[20];
  const float* dec_l2_w     = (const float*)d_in[21];
  const float* dec_l2_b     = (const float*)d_in[22];
  const float* dec_ln1_g    = (const float*)d_in[23];
  const float* dec_ln1_b    = (const float*)d_in[24];
  const float* dec_ln2_g    = (const float*)d_in[25];
  const float* dec_ln2_b    = (const float*)d_in[26];
  const float* dec_ln3_g    = (const float*)d_in[27];
  const float* dec_ln3_b    = (const float*)d_in[28];
  const float* head1_w      = (const float*)d_in[29];
  const float* head1_b      = (const float*)d_in[30];
  const float* head2_w      = (const float*)d_in[31];
  const float* head2_b      = (const float*)d_in[32];
  const int*   query_idx    = (const int*)d_in[33];
  float* out = (float*)d_out;

  const int DD  = Dd * Dd;
  const int IN3 = 3 * Dd * Dd;
  const int FF  = HIDh * Dd;
  const int MD  = Mm * Dd;

  float* ws = (float*)d_ws;
  float* ABSUM = ws;
  float* ALPHA = ws + 64;
  float* INVA  = ws + 128;
  float* STAT  = ws + 256;                 // NSTAT tables x 1024 rows x 2
  const int STATF = NSTAT * Mm * 2;        // 40960 floats
  float* H   = STAT + STATF;
  float* MEM = H   + MD;
  float* SCR = MEM + MD;                   // patchify scratch / stem residual
  float* CTX = SCR + MD;
  float* QKV = CTX + MD;
  size_t act_floats = 256 + (size_t)STATF + 4 * (size_t)MD + (size_t)Mm * HIDh;
  short* WQ = (short*)(ws + act_floats);
  const size_t WQ_ELEMS = (size_t)DD + 4 * ((size_t)IN3 + DD + FF + FF)
                        + 4 * ((size_t)IN3 + DD + IN3 + DD + FF + FF)
                        + 2 * (size_t)FF;
  const bool use_wq = ws_size >= act_floats * 4 + WQ_ELEMS * 2;

  auto T = [&](int i) { return STAT + (size_t)i * (Mm * 2); };

  QJobs jobs;
  int j = 0; int off = 0;
  auto addjob = [&](const float* p, int n) { jobs.ptr[j] = p; jobs.n[j] = n; jobs.off[j] = off; off += n; j++; };
  addjob(lin_enc_w, DD);
  for (int l = 0; l < NLl; ++l) addjob(enc_in_w  + (size_t)l * IN3, IN3);
  for (int l = 0; l < NLl; ++l) addjob(enc_out_w + (size_t)l * DD,  DD);
  for (int l = 0; l < NLl; ++l) addjob(enc_l1_w  + (size_t)l * FF,  FF);
  for (int l = 0; l < NLl; ++l) addjob(enc_l2_w  + (size_t)l * FF,  FF);
  for (int l = 0; l < NLl; ++l) addjob(dec_sa_in_w  + (size_t)l * IN3, IN3);
  for (int l = 0; l < NLl; ++l) addjob(dec_sa_out_w + (size_t)l * DD,  DD);
  for (int l = 0; l < NLl; ++l) addjob(dec_ca_in_w  + (size_t)l * IN3, IN3);
  for (int l = 0; l < NLl; ++l) addjob(dec_ca_out_w + (size_t)l * DD,  DD);
  for (int l = 0; l < NLl; ++l) addjob(dec_l1_w + (size_t)l * FF, FF);
  for (int l = 0; l < NLl; ++l) addjob(dec_l2_w + (size_t)l * FF, FF);
  addjob(head1_w, FF);
  addjob(head2_w, FF);

  const int ZN = 256 + STATF;
  k_zero<<<(ZN + 255) / 256, 256, 0, stream>>>(ws, ZN);
  k_abssum<<<NJOBS * 64, 256, 0, stream>>>(jobs, ABSUM);
  k_alpha<<<1, 64, 0, stream>>>(jobs, ABSUM, ALPHA, INVA);
  if (use_wq) k_quant<<<NJOBS * 128, 256, 0, stream>>>(jobs, INVA, WQ);

  auto gemm = [&](const float* Xa, const float* Xb, int n_split, int ldx,
                  const float* qe, const float* lng, const float* lnb,
                  const float* statA, const float* statB,
                  const float* W, int slot, const float* bias, const float* pos,
                  const float* res, int ldr,
                  float* o, int ldo, float* o2, float* statOut,
                  int N, int K, int relu) {
    dim3 grid(N / NT, Mm / MT);
    const short* wq = use_wq ? WQ + (size_t)jobs.off[slot] : nullptr;
    const float* wr = use_wq ? nullptr : W;
    k_gemm_mfma<<<grid, 256, 0, stream>>>(Xa, Xb, n_split, ldx, qe, query_idx,
                                          lng, lnb, statA, statB,
                                          wr, wq, bias, pos, res, ldr,
                                          o, ldo, o2, statOut,
                                          N, K, ALPHA, INVA, slot, relu);
  };

  const float scale = 1.f / sqrtf((float)HDd);
  auto attn = [&](const float* out_w, int out_slot, float* statOut) {
    k_attn<<<dim3(Ss / 64, Bb * NHh), 256, 0, stream>>>(QKV, CTX, scale);
    gemm(CTX, nullptr, 0, Dd, nullptr, nullptr, nullptr, nullptr, nullptr,
         out_w, out_slot, nullptr, nullptr, H, Dd, H, Dd, nullptr, statOut,
         Dd, Dd, 0);
  };

  const int NELEM = Mm * Dd;
  const int EB = (NELEM + 255) / 256;

  // ---- stem: H = qlinear(t)+t+pos ; stats -> T0 (enc0 ln1) ----
  k_patchify<<<EB, 256, 0, stream>>>(x, SCR);
  gemm(SCR, nullptr, 0, Dd, nullptr, nullptr, nullptr, nullptr, nullptr,
       lin_enc_w, 0, lin_enc_b, pos_emb, SCR, Dd, H, Dd, nullptr, T(0),
       Dd, Dd, 0);

  // ---- encoder ----
  for (int l = 0; l < NLl; ++l) {
    gemm(H, nullptr, 0, Dd, nullptr, enc_ln1_g + l * Dd, enc_ln1_b + l * Dd,
         T(2 * l), nullptr,
         enc_in_w + (size_t)l * IN3, 1 + l,
         nullptr, nullptr, nullptr, 0, QKV, 1728, nullptr, nullptr, 1728, Dd, 0);
    attn(enc_out_w + (size_t)l * DD, 5 + l, T(2 * l + 1));
    gemm(H, nullptr, 0, Dd, nullptr, enc_ln2_g + l * Dd, enc_ln2_b + l * Dd,
         T(2 * l + 1), nullptr,
         enc_l1_w + (size_t)l * FF, 9 + l,
         enc_l1_b + l * HIDh, nullptr, nullptr, 0, QKV, HIDh, nullptr, nullptr,
         HIDh, Dd, 1);
    gemm(QKV, nullptr, 0, HIDh, nullptr, nullptr, nullptr, nullptr, nullptr,
         enc_l2_w + (size_t)l * FF, 13 + l,
         enc_l2_b + l * Dd, nullptr, H, Dd, H, Dd,
         (l == NLl - 1) ? MEM : nullptr, T(2 * l + 2), Dd, HIDh, 0);
  }

  // ---- decoder ----
  for (int l = 0; l < NLl; ++l) {
    float* ln1s = T(8 + 3 * l);
    // merged SA-in: cols [0,1152) A=LN(H)+qe (Q,K), cols [1152,1728) B=LN(H) (V)
    gemm(H, H, 2 * Dd, Dd, query_embed,
         dec_ln1_g + l * Dd, dec_ln1_b + l * Dd, ln1s, ln1s,
         dec_sa_in_w + (size_t)l * IN3, 17 + l,
         nullptr, nullptr, nullptr, 0, QKV, 1728, nullptr, nullptr, 1728, Dd, 0);
    attn(dec_sa_out_w + (size_t)l * DD, 21 + l, T(9 + 3 * l));
    // merged CA-in: cols [0,576) A=LN(H)+qe (Q), cols [576,1728) B=MEM raw (K,V)
    gemm(H, MEM, Dd, Dd, query_embed,
         dec_ln2_g + l * Dd, dec_ln2_b + l * Dd, T(9 + 3 * l), nullptr,
         dec_ca_in_w + (size_t)l * IN3, 25 + l,
         nullptr, nullptr, nullptr, 0, QKV, 1728, nullptr, nullptr, 1728, Dd, 0);
    attn(dec_ca_out_w + (size_t)l * DD, 29 + l, T(10 + 3 * l));
    gemm(H, nullptr, 0, Dd, nullptr, dec_ln3_g + l * Dd, dec_ln3_b + l * Dd,
         T(10 + 3 * l), nullptr,
         dec_l1_w + (size_t)l * FF, 33 + l,
         dec_l1_b + l * HIDh, nullptr, nullptr, 0, QKV, HIDh, nullptr, nullptr,
         HIDh, Dd, 1);
    gemm(QKV, nullptr, 0, HIDh, nullptr, nullptr, nullptr, nullptr, nullptr,
         dec_l2_w + (size_t)l * FF, 37 + l,
         dec_l2_b + l * Dd, nullptr, H, Dd, H, Dd, nullptr,
         (l < NLl - 1) ? T(11 + 3 * l) : nullptr, Dd, HIDh, 0);
  }

  // ---- head (no LN) ----
  gemm(H, nullptr, 0, Dd, nullptr, nullptr, nullptr, nullptr, nullptr,
       head1_w, 41, head1_b, nullptr, nullptr, 0, QKV, HIDh, nullptr, nullptr,
       HIDh, Dd, 1);
  gemm(QKV, nullptr, 0, HIDh, nullptr, nullptr, nullptr, nullptr, nullptr,
       head2_w, 42, head2_b, nullptr, H, Dd, H, Dd, nullptr, nullptr,
       Dd, HIDh, 0);

  // ---- output ----
  k_unpatch<<<EB, 256, 0, stream>>>(H, out);
}

// Round 7
// 1330.347 us; speedup vs baseline: 1.3128x; 1.1509x over previous
//
#include <hip/hip_runtime.h>
#include <cstddef>

#define Pp    3
#define Cc    64
#define IMGi  48
#define Gg    16
#define Dd    576
#define NHh   12
#define HDd   48
#define HIDh  2304
#define NLl   4
#define Ss    256
#define Bb    4
#define Mm    1024          // S*B tokens
#define EPSf  1e-5f
#define NJOBS 43
#define NSTAT 20            // per-site LN stat tables (sum, sumsq) per row

typedef short short8 __attribute__((ext_vector_type(8)));
typedef short short4v __attribute__((ext_vector_type(4)));
typedef float f32x4  __attribute__((ext_vector_type(4)));
typedef unsigned short ushort_t;

struct QJobs { const float* ptr[NJOBS]; int n[NJOBS]; int off[NJOBS]; };

// float -> bf16 (RNE), bit-level
__device__ __forceinline__ short f2bf(float f) {
  unsigned u = __float_as_uint(f);
  u = u + 0x7fffu + ((u >> 16) & 1u);
  return (short)(u >> 16);
}
__device__ __forceinline__ float bf2f(short s) {
  return __uint_as_float(((unsigned)(unsigned short)s) << 16);
}

// async global->LDS, 16B per lane. dst must be wave-uniform; HW adds lane*16.
typedef __attribute__((address_space(3))) unsigned lds_u32;
typedef __attribute__((address_space(1))) const unsigned glob_u32;
__device__ __forceinline__ void gload_lds16(const void* g, void* l) {
  __builtin_amdgcn_global_load_lds((glob_u32*)g, (lds_u32*)l, 16, 0, 0);
}

// ---------------- small utility kernels ----------------

__global__ void k_zero(float* p, int n) {
  int i = blockIdx.x * blockDim.x + threadIdx.x;
  if (i < n) p[i] = 0.f;
}

__global__ void k_abssum(QJobs jobs, float* absum) {
  int job = blockIdx.x >> 6, blk = blockIdx.x & 63;
  const float4* p4 = (const float4*)jobs.ptr[job];
  int n4 = jobs.n[job] >> 2;
  float s0 = 0.f, s1 = 0.f, s2 = 0.f, s3 = 0.f;
  for (int i = blk * 1024 + threadIdx.x; i < n4; i += 64 * 1024) {
    float4 v = p4[i];
    s0 += fabsf(v.x) + fabsf(v.y) + fabsf(v.z) + fabsf(v.w);
    int i1 = i + 256;
    if (i1 < n4) { float4 w = p4[i1]; s1 += fabsf(w.x) + fabsf(w.y) + fabsf(w.z) + fabsf(w.w); }
    int i2 = i + 512;
    if (i2 < n4) { float4 w = p4[i2]; s2 += fabsf(w.x) + fabsf(w.y) + fabsf(w.z) + fabsf(w.w); }
    int i3 = i + 768;
    if (i3 < n4) { float4 w = p4[i3]; s3 += fabsf(w.x) + fabsf(w.y) + fabsf(w.z) + fabsf(w.w); }
  }
  float s = (s0 + s1) + (s2 + s3);
  #pragma unroll
  for (int o = 32; o; o >>= 1) s += __shfl_xor(s, o);
  __shared__ float red[4];
  if ((threadIdx.x & 63) == 0) red[threadIdx.x >> 6] = s;
  __syncthreads();
  if (threadIdx.x == 0) atomicAdd(&absum[job], (red[0] + red[1]) + (red[2] + red[3]));
}

__global__ void k_alpha(QJobs jobs, const float* absum, float* alpha, float* inva) {
  int j = threadIdx.x;
  if (j < NJOBS) {
    float a = 2.f * (absum[j] / (float)jobs.n[j]) / sqrtf(7.f);
    alpha[j] = a;
    inva[j] = 1.f / a;
  }
}

// pre-quantize all weights: wq = bf16( rint(clamp(w/alpha,-8,7)) )
__global__ void k_quant(QJobs jobs, const float* __restrict__ inva, short* __restrict__ wq) {
  int job = blockIdx.x >> 7, blk = blockIdx.x & 127;
  const float* p = jobs.ptr[job];
  int n8 = jobs.n[job] >> 3;
  short* dst = wq + (size_t)jobs.off[job];
  float ia = inva[job];
  for (int i = blk * 512 + threadIdx.x; i < n8; i += 128 * 512) {
    const float4* p4 = (const float4*)(p + (size_t)i * 8);
    float4 w0 = p4[0], w1 = p4[1];
    int i1 = i + 256;
    float4 w2, w3;
    bool has2 = i1 < n8;
    if (has2) { const float4* q4 = (const float4*)(p + (size_t)i1 * 8); w2 = q4[0]; w3 = q4[1]; }
    short8 bv;
    bv[0] = f2bf(rintf(fminf(7.f, fmaxf(-8.f, w0.x * ia))));
    bv[1] = f2bf(rintf(fminf(7.f, fmaxf(-8.f, w0.y * ia))));
    bv[2] = f2bf(rintf(fminf(7.f, fmaxf(-8.f, w0.z * ia))));
    bv[3] = f2bf(rintf(fminf(7.f, fmaxf(-8.f, w0.w * ia))));
    bv[4] = f2bf(rintf(fminf(7.f, fmaxf(-8.f, w1.x * ia))));
    bv[5] = f2bf(rintf(fminf(7.f, fmaxf(-8.f, w1.y * ia))));
    bv[6] = f2bf(rintf(fminf(7.f, fmaxf(-8.f, w1.z * ia))));
    bv[7] = f2bf(rintf(fminf(7.f, fmaxf(-8.f, w1.w * ia))));
    *(short8*)(dst + (size_t)i * 8) = bv;
    if (has2) {
      short8 cv;
      cv[0] = f2bf(rintf(fminf(7.f, fmaxf(-8.f, w2.x * ia))));
      cv[1] = f2bf(rintf(fminf(7.f, fmaxf(-8.f, w2.y * ia))));
      cv[2] = f2bf(rintf(fminf(7.f, fmaxf(-8.f, w2.z * ia))));
      cv[3] = f2bf(rintf(fminf(7.f, fmaxf(-8.f, w2.w * ia))));
      cv[4] = f2bf(rintf(fminf(7.f, fmaxf(-8.f, w3.x * ia))));
      cv[5] = f2bf(rintf(fminf(7.f, fmaxf(-8.f, w3.y * ia))));
      cv[6] = f2bf(rintf(fminf(7.f, fmaxf(-8.f, w3.z * ia))));
      cv[7] = f2bf(rintf(fminf(7.f, fmaxf(-8.f, w3.w * ia))));
      *(short8*)(dst + (size_t)i1 * 8) = cv;
    }
  }
}

// x:(B,C,48,48) fp32 -> t:(S,B,D) fp32 + bf16 ; row = s*B+b
__global__ void k_patchify(const float* __restrict__ x, float* __restrict__ t,
                           ushort_t* __restrict__ tb) {
  int i = blockIdx.x * 256 + threadIdx.x;
  if (i >= Mm * Dd) return;
  int d = i % Dd, row = i / Dd;
  int b = row % Bb, s = row / Bb;
  int c = d / 9, r = d % 9;
  int p1 = r / 3, p2 = r % 3;
  int g1 = s / Gg, g2 = s % Gg;
  float v = x[((size_t)(b * Cc + c) * IMGi + (g1 * Pp + p1)) * IMGi + (g2 * Pp + p2)];
  t[i] = v;
  tb[i] = (ushort_t)f2bf(v);
}

// H:(S,B,D) fp32 -> out:(B,C,48,48) fp32
__global__ void k_unpatch(const float* __restrict__ h, float* __restrict__ out) {
  int i = blockIdx.x * 256 + threadIdx.x;
  if (i >= Bb * Cc * IMGi * IMGi) return;
  int j = i % IMGi, t = i / IMGi;
  int r = t % IMGi; t /= IMGi;
  int c = t % Cc;
  int b = t / Cc;
  int g1 = r / Pp, p1 = r % Pp, g2 = j / Pp, p2 = j % Pp;
  int s = g1 * Gg + g2;
  int d = c * 9 + p1 * 3 + p2;
  out[i] = h[(size_t)(s * Bb + b) * Dd + d];
}

// ---------------- MFMA GEMM ------------------------------------------------
// Block: 256 thr (4 waves), tile 64x64, wave tile 32x32 (4x mfma 16x16x32).
// K multiple of 288. LDS 2 x 38 KB -> 2 blocks/CU.
// A and B both bf16, both staged into padded (304-short) swizzled LDS images.
// No-LN A panels and all Wq B panels use async global_load_lds (inverse-
// swizzled source); LN(+qe) A panels reg-stage through the same layout.
// LN uses per-row (sum,sumsq) tables filled by producer epilogues (atomics).
#define MT 64
#define NT 64
#define KC 288
#define LDKB 304   // row stride in shorts (608 B)
#define BCHUNKS 38 // 64*304 shorts / 512 shorts-per-1KB-chunk

__device__ __forceinline__ int bswz(int row, int colByte) {
  return row * (LDKB * 2) + (colByte ^ (((row >> 2) & 3) << 4));
}

// async panel stage: 64 rows x 288 shorts from base (row stride ld shorts)
__device__ __forceinline__ void stage_async(const ushort_t* base, int ld,
                                            char* lds, int wave, int lane) {
  #pragma unroll
  for (int j = 0; j < 10; ++j) {
    const int c = wave * 10 + j;          // wave-uniform chunk id
    if (c < BCHUNKS) {
      const int p = c * 512 + lane * 8;   // physical short index
      const int prow = p / LDKB;
      const int pcol2 = (p % LDKB) * 2;   // physical byte col in [0,608)
      const int lcol = pcol2 ^ (((prow >> 2) & 3) << 4);
      const ushort_t* src = (lcol < 576)
        ? base + (size_t)prow * ld + (lcol >> 1)
        : base;                           // pad slot, never read
      gload_lds16(src, lds + c * 1024);
    }
  }
}

__global__ __launch_bounds__(256)
void k_gemm_mfma(const ushort_t* __restrict__ Xa, const ushort_t* __restrict__ Xb,
                 int n_split, int ldx,
                 const float* __restrict__ qe, const int* __restrict__ qidx,
                 const float* __restrict__ lng, const float* __restrict__ lnb,
                 const float* __restrict__ statA, const float* __restrict__ statB,
                 const float* __restrict__ Wraw, const short* __restrict__ Wq,
                 const float* __restrict__ bias, const float* __restrict__ pos,
                 const float* res, int ldr,
                 float* out, int ldo,
                 ushort_t* outbf, ushort_t* outbf2, float* statOut,
                 int N, int K,
                 const float* __restrict__ alpha_p, const float* __restrict__ inva_p,
                 int slot, int relu)
{
  __shared__ short As[NT * LDKB];
  __shared__ short Bs[NT * LDKB];
  const int tid  = threadIdx.x;
  const int wave = tid >> 6, lane = tid & 63;
  const int quad = lane >> 4, l15 = lane & 15;
  const int tile_m = blockIdx.y * MT, tile_n = blockIdx.x * NT;
  const int m_off = (wave >> 1) * 32, n_off = (wave & 1) * 32;
  const int sr = tid >> 2;           // staging row 0..63
  const int sc = (tid & 3) * 8;      // staging col start (shorts), stride 32
  const float inva = inva_p[slot];

  const bool isA = (!Xb || tile_n < n_split);
  const ushort_t* X = isA ? Xa : Xb;
  const bool addqe = (qe != nullptr) && isA;
  const float* stat = isA ? statA : statB;
  const bool a_reg = (stat != nullptr) || addqe;
  size_t qe_off = 0;
  if (addqe) qe_off = (size_t)qidx[0] * ((size_t)Ss * Dd);

  // per-row LN params from stat table (single read per staging thread)
  float mean = 0.f, sinv = 1.f;
  if (stat) {
    float2 st = *(const float2*)&stat[2 * (tile_m + sr)];
    mean = st.x * (1.f / (float)Dd);
    float var = st.y * (1.f / (float)Dd) - mean * mean;
    sinv = rsqrtf(var + EPSf);
  }

  f32x4 acc00 = {0,0,0,0}, acc01 = {0,0,0,0}, acc10 = {0,0,0,0}, acc11 = {0,0,0,0};

  for (int kc = 0; kc < K; kc += KC) {
    // ---- B panel ----
    if (Wq) {
      stage_async((const ushort_t*)Wq + (size_t)tile_n * K + kc, K,
                  (char*)Bs, wave, lane);
    } else {
      const float* wr = Wraw + (size_t)(tile_n + sr) * K + kc;
      #pragma unroll
      for (int j = 0; j < 9; ++j) {
        const int k = sc + j * 32;
        float4 w0 = *(const float4*)(wr + k);
        float4 w1 = *(const float4*)(wr + k + 4);
        short8 bv;
        bv[0] = f2bf(rintf(fminf(7.f, fmaxf(-8.f, w0.x * inva))));
        bv[1] = f2bf(rintf(fminf(7.f, fmaxf(-8.f, w0.y * inva))));
        bv[2] = f2bf(rintf(fminf(7.f, fmaxf(-8.f, w0.z * inva))));
        bv[3] = f2bf(rintf(fminf(7.f, fmaxf(-8.f, w0.w * inva))));
        bv[4] = f2bf(rintf(fminf(7.f, fmaxf(-8.f, w1.x * inva))));
        bv[5] = f2bf(rintf(fminf(7.f, fmaxf(-8.f, w1.y * inva))));
        bv[6] = f2bf(rintf(fminf(7.f, fmaxf(-8.f, w1.z * inva))));
        bv[7] = f2bf(rintf(fminf(7.f, fmaxf(-8.f, w1.w * inva))));
        *(short8*)((char*)Bs + bswz(sr, k * 2)) = bv;
      }
    }

    // ---- A panel ----
    if (!a_reg) {
      stage_async(X + (size_t)tile_m * ldx + kc, ldx, (char*)As, wave, lane);
    } else {
      const int arow = tile_m + sr;
      const ushort_t* xr = X + (size_t)arow * ldx + kc;
      const float* qr = addqe ? (qe + qe_off + (size_t)(arow >> 2) * Dd + kc) : nullptr;
      #pragma unroll
      for (int j = 0; j < 9; ++j) {
        const int k = sc + j * 32;
        short8 xv = *(const short8*)(xr + k);
        float a[8];
        #pragma unroll
        for (int e = 0; e < 8; ++e) a[e] = bf2f(xv[e]);
        if (stat) {
          float4 g0 = *(const float4*)(lng + kc + k);
          float4 g1 = *(const float4*)(lng + kc + k + 4);
          float4 b0 = *(const float4*)(lnb + kc + k);
          float4 b1 = *(const float4*)(lnb + kc + k + 4);
          a[0] = (a[0] - mean) * sinv * g0.x + b0.x;
          a[1] = (a[1] - mean) * sinv * g0.y + b0.y;
          a[2] = (a[2] - mean) * sinv * g0.z + b0.z;
          a[3] = (a[3] - mean) * sinv * g0.w + b0.w;
          a[4] = (a[4] - mean) * sinv * g1.x + b1.x;
          a[5] = (a[5] - mean) * sinv * g1.y + b1.y;
          a[6] = (a[6] - mean) * sinv * g1.z + b1.z;
          a[7] = (a[7] - mean) * sinv * g1.w + b1.w;
        }
        if (addqe) {
          float4 q0 = *(const float4*)(qr + k);
          float4 q1 = *(const float4*)(qr + k + 4);
          a[0] += q0.x; a[1] += q0.y; a[2] += q0.z; a[3] += q0.w;
          a[4] += q1.x; a[5] += q1.y; a[6] += q1.z; a[7] += q1.w;
        }
        short8 av;
        #pragma unroll
        for (int e = 0; e < 8; ++e) av[e] = f2bf(a[e]);
        *(short8*)((char*)As + bswz(sr, k * 2)) = av;
      }
    }
    __syncthreads();   // drains vmcnt incl. global_load_lds

    // ---- compute: 9 k-steps, barrier-free ----
    #pragma unroll 3
    for (int ks = 0; ks < KC / 32; ++ks) {
      const int kb = ks * 32 + quad * 8;
      short8 af0 = *(const short8*)((const char*)As + bswz(m_off + l15, kb * 2));
      short8 af1 = *(const short8*)((const char*)As + bswz(m_off + 16 + l15, kb * 2));
      short8 bf0 = *(const short8*)((const char*)Bs + bswz(n_off + l15, kb * 2));
      short8 bf1 = *(const short8*)((const char*)Bs + bswz(n_off + 16 + l15, kb * 2));
      acc00 = __builtin_amdgcn_mfma_f32_16x16x32_bf16(af0, bf0, acc00, 0, 0, 0);
      acc01 = __builtin_amdgcn_mfma_f32_16x16x32_bf16(af0, bf1, acc01, 0, 0, 0);
      acc10 = __builtin_amdgcn_mfma_f32_16x16x32_bf16(af1, bf0, acc10, 0, 0, 0);
      acc11 = __builtin_amdgcn_mfma_f32_16x16x32_bf16(af1, bf1, acc11, 0, 0, 0);
    }
    __syncthreads();
  }

  // ---- epilogue ----
  const float a_s = alpha_p[slot];
  const int rowb = tile_m + m_off + quad * 4;
  const int colb = tile_n + n_off + l15;
  f32x4 accs[4] = {acc00, acc01, acc10, acc11};
  float vsum[2][4], vsq[2][4];
  #pragma unroll
  for (int rt = 0; rt < 2; ++rt)
    #pragma unroll
    for (int r = 0; r < 4; ++r) { vsum[rt][r] = 0.f; vsq[rt][r] = 0.f; }

  #pragma unroll
  for (int t = 0; t < 4; ++t) {
    int row0 = rowb + ((t >> 1) * 16);
    int col  = colb + ((t & 1) * 16);
    float bv = bias ? bias[col] : 0.f;
    #pragma unroll
    for (int r = 0; r < 4; ++r) {
      int row = row0 + r;
      float v = accs[t][r] * a_s + bv;
      if (res) v += res[(size_t)row * ldr + col];
      if (pos) v += pos[(size_t)(row >> 2) * Dd + col];
      if (relu) v = fmaxf(v, 0.f);
      if (out)    out[(size_t)row * ldo + col] = v;
      if (outbf)  outbf[(size_t)row * ldo + col]  = (ushort_t)f2bf(v);
      if (outbf2) outbf2[(size_t)row * ldo + col] = (ushort_t)f2bf(v);
      vsum[t >> 1][r] += v;
      vsq[t >> 1][r]  += v * v;
    }
  }

  // ---- per-row LN-stat accumulation for downstream consumers ----
  if (statOut) {
    #pragma unroll
    for (int rt = 0; rt < 2; ++rt) {
      #pragma unroll
      for (int r = 0; r < 4; ++r) {
        float s = vsum[rt][r], q = vsq[rt][r];
        #pragma unroll
        for (int o = 1; o < 16; o <<= 1) {
          s += __shfl_xor(s, o);
          q += __shfl_xor(q, o);
        }
        if (l15 == 0) {
          int row = rowb + rt * 16 + r;
          atomicAdd(&statOut[2 * row],     s);
          atomicAdd(&statOut[2 * row + 1], q);
        }
      }
    }
  }
}

// ---------------- fused flash attention (bf16 in, bf16 out) ----------------
__global__ __launch_bounds__(256)
void k_attn(const ushort_t* __restrict__ QKV, ushort_t* __restrict__ ctx, float scale) {
  __shared__ short Ks[256][72];   // [ki][d]  d 48..63 zero-padded
  __shared__ short Qs[64][72];    // [qi][d]  zero-padded
  __shared__ short Vt[48][264];   // [d][ki]
  __shared__ short Pq[64][264];   // [qi][ki]
  const int qt = blockIdx.x;
  const int b  = blockIdx.y / NHh, h = blockIdx.y % NHh;
  const int tid = threadIdx.x;
  const int w = tid >> 6, lane = tid & 63, quad = lane >> 4, l15 = lane & 15;

  {
    const ushort_t* kp = QKV + (size_t)(tid * Bb + b) * 1728 + Dd + h * HDd;
    #pragma unroll
    for (int d0 = 0; d0 < 48; d0 += 8)
      *(short8*)&Ks[tid][d0] = *(const short8*)(kp + d0);
    short4v z = {0, 0, 0, 0};
    *(short4v*)&Ks[tid][48] = z; *(short4v*)&Ks[tid][52] = z;
    *(short4v*)&Ks[tid][56] = z; *(short4v*)&Ks[tid][60] = z;
    const ushort_t* vp = QKV + (size_t)(tid * Bb + b) * 1728 + 2 * Dd + h * HDd;
    #pragma unroll
    for (int d0 = 0; d0 < 48; d0 += 8) {
      short8 v = *(const short8*)(vp + d0);
      #pragma unroll
      for (int e = 0; e < 8; ++e) Vt[d0 + e][tid] = v[e];
    }
    if (tid < 64) {
      const ushort_t* qp = QKV + (size_t)((qt * 64 + tid) * Bb + b) * 1728 + h * HDd;
      #pragma unroll
      for (int d0 = 0; d0 < 48; d0 += 8)
        *(short8*)&Qs[tid][d0] = *(const short8*)(qp + d0);
      *(short4v*)&Qs[tid][48] = z; *(short4v*)&Qs[tid][52] = z;
      *(short4v*)&Qs[tid][56] = z; *(short4v*)&Qs[tid][60] = z;
    }
  }
  __syncthreads();

  short8 bq0 = *(short8*)&Qs[w * 16 + l15][quad * 8];
  short8 bq1 = *(short8*)&Qs[w * 16 + l15][32 + quad * 8];
  f32x4 sf[16];
  #pragma unroll
  for (int mt = 0; mt < 16; ++mt) {
    f32x4 acc = {0, 0, 0, 0};
    short8 a0 = *(short8*)&Ks[mt * 16 + l15][quad * 8];
    short8 a1 = *(short8*)&Ks[mt * 16 + l15][32 + quad * 8];
    acc = __builtin_amdgcn_mfma_f32_16x16x32_bf16(a0, bq0, acc, 0, 0, 0);
    acc = __builtin_amdgcn_mfma_f32_16x16x32_bf16(a1, bq1, acc, 0, 0, 0);
    sf[mt] = acc;
  }

  float mx = -1e30f;
  #pragma unroll
  for (int mt = 0; mt < 16; ++mt)
    #pragma unroll
    for (int r = 0; r < 4; ++r) {
      sf[mt][r] *= scale;
      mx = fmaxf(mx, sf[mt][r]);
    }
  mx = fmaxf(mx, __shfl_xor(mx, 16));
  mx = fmaxf(mx, __shfl_xor(mx, 32));
  float sum = 0.f;
  #pragma unroll
  for (int mt = 0; mt < 16; ++mt)
    #pragma unroll
    for (int r = 0; r < 4; ++r) {
      float e = __expf(sf[mt][r] - mx);
      sf[mt][r] = e;
      sum += e;
    }
  sum += __shfl_xor(sum, 16);
  sum += __shfl_xor(sum, 32);
  float inv = 1.f / sum;

  #pragma unroll
  for (int mt = 0; mt < 16; ++mt) {
    short4v p = { f2bf(sf[mt][0] * inv), f2bf(sf[mt][1] * inv),
                  f2bf(sf[mt][2] * inv), f2bf(sf[mt][3] * inv) };
    *(short4v*)&Pq[w * 16 + l15][mt * 16 + quad * 4] = p;
  }
  __syncthreads();

  f32x4 of0 = {0,0,0,0}, of1 = {0,0,0,0}, of2 = {0,0,0,0};
  #pragma unroll
  for (int kt = 0; kt < 8; ++kt) {
    short8 a = *(short8*)&Pq[w * 16 + l15][kt * 32 + quad * 8];
    short8 b0 = *(short8*)&Vt[l15][kt * 32 + quad * 8];
    short8 b1 = *(short8*)&Vt[16 + l15][kt * 32 + quad * 8];
    short8 b2 = *(short8*)&Vt[32 + l15][kt * 32 + quad * 8];
    of0 = __builtin_amdgcn_mfma_f32_16x16x32_bf16(a, b0, of0, 0, 0, 0);
    of1 = __builtin_amdgcn_mfma_f32_16x16x32_bf16(a, b1, of1, 0, 0, 0);
    of2 = __builtin_amdgcn_mfma_f32_16x16x32_bf16(a, b2, of2, 0, 0, 0);
  }
  const int qg = qt * 64 + w * 16 + quad * 4;
  #pragma unroll
  for (int r = 0; r < 4; ++r) {
    ushort_t* cr = ctx + (size_t)((qg + r) * Bb + b) * Dd + h * HDd + l15;
    cr[0]  = (ushort_t)f2bf(of0[r]);
    cr[16] = (ushort_t)f2bf(of1[r]);
    cr[32] = (ushort_t)f2bf(of2[r]);
  }
}

// ---------------- host ----------------

extern "C" void kernel_launch(void* const* d_in, const int* in_sizes, int n_in,
                              void* d_out, int out_size, void* d_ws, size_t ws_size,
                              hipStream_t stream) {
  (void)in_sizes; (void)n_in; (void)out_size;
  const float* x            = (const float*)d_in[0];
  const float* lin_enc_w    = (const float*)d_in[1];
  const float* lin_enc_b    = (const float*)d_in[2];
  const float* pos_emb      = (const float*)d_in[3];
  const float* query_embed  = (const float*)d_in[4];
  const float* enc_in_w     = (const float*)d_in[5];
  const float* enc_out_w    = (const float*)d_in[6];
  const float* enc_l1_w     = (const float*)d_in[7];
  const float* enc_l1_b     = (const float*)d_in[8];
  const float* enc_l2_w     = (const float*)d_in[9];
  const float* enc_l2_b     = (const float*)d_in[10];
  const float* enc_ln1_g    = (const float*)d_in[11];
  const float* enc_ln1_b    = (const float*)d_in[12];
  const float* enc_ln2_g    = (const float*)d_in[13];
  const float* enc_ln2_b    = (const float*)d_in[14];
  const float* dec_sa_in_w  = (const float*)d_in[15];
  const float* dec_sa_out_w = (const float*)d_in[16];
  const float* dec_ca_in_w  = (const float*)d_in[17];
  const float* dec_ca_out_w = (const float*)d_in[18];
  const float* dec_l1_w     = (const float*)d_in[19];
  const float* dec_l1_b     = (const float*)d_in[20];
  const float* dec_l2_w     = (const float*)d_in[21];
  const float* dec_l2_b     = (const float*)d_in[22];
  const float* dec_ln1_g    = (const float*)d_in[23];
  const float* dec_ln1_b    = (const float*)d_in[24];
  const float* dec_ln2_g    = (const float*)d_in[25];
  const float* dec_ln2_b    = (const float*)d_in[26];
  const float* dec_ln3_g    = (const float*)d_in[27];
  const float* dec_ln3_b    = (const float*)d_in[28];
  const float* head1_w      = (const float*)d_in[29];
  const float* head1_b      = (const float*)d_in[30];
  const float* head2_w      = (const float*)d_in[31];
  const float* head2_b      = (const float*)d_in[32];
  const int*   query_idx    = (const int*)d_in[33];
  float* out = (float*)d_out;

  const int DD  = Dd * Dd;
  const int IN3 = 3 * Dd * Dd;
  const int FF  = HIDh * Dd;
  const int MD  = Mm * Dd;

  float* ws = (float*)d_ws;
  float* ABSUM = ws;
  float* ALPHA = ws + 64;
  float* INVA  = ws + 128;
  float* STAT  = ws + 256;                 // NSTAT tables x 1024 rows x 2
  const int STATF = NSTAT * Mm * 2;        // 40960 floats
  float* H   = STAT + STATF;               // fp32 residual master
  float* SCR = H + MD;                     // fp32 patchify (stem residual)
  ushort_t* Hb   = (ushort_t*)(SCR + MD);  // bf16 companions / activations
  ushort_t* SCRb = Hb + MD;
  ushort_t* MEMb = SCRb + MD;
  ushort_t* CTXb = MEMb + MD;
  ushort_t* QKVb = CTXb + MD;              // Mm x 1728 (qkv) / Mm x 2304 (ffn)
  size_t act_bytes = (256 + (size_t)STATF + 2 * (size_t)MD) * 4
                   + (4 * (size_t)MD + (size_t)Mm * HIDh) * 2;
  short* WQ = (short*)(QKVb + (size_t)Mm * HIDh);
  const size_t WQ_ELEMS = (size_t)DD + 4 * ((size_t)IN3 + DD + FF + FF)
                        + 4 * ((size_t)IN3 + DD + IN3 + DD + FF + FF)
                        + 2 * (size_t)FF;
  const bool use_wq = ws_size >= act_bytes + WQ_ELEMS * 2;

  auto T = [&](int i) { return STAT + (size_t)i * (Mm * 2); };

  QJobs jobs;
  int j = 0; int off = 0;
  auto addjob = [&](const float* p, int n) { jobs.ptr[j] = p; jobs.n[j] = n; jobs.off[j] = off; off += n; j++; };
  addjob(lin_enc_w, DD);
  for (int l = 0; l < NLl; ++l) addjob(enc_in_w  + (size_t)l * IN3, IN3);
  for (int l = 0; l < NLl; ++l) addjob(enc_out_w + (size_t)l * DD,  DD);
  for (int l = 0; l < NLl; ++l) addjob(enc_l1_w  + (size_t)l * FF,  FF);
  for (int l = 0; l < NLl; ++l) addjob(enc_l2_w  + (size_t)l * FF,  FF);
  for (int l = 0; l < NLl; ++l) addjob(dec_sa_in_w  + (size_t)l * IN3, IN3);
  for (int l = 0; l < NLl; ++l) addjob(dec_sa_out_w + (size_t)l * DD,  DD);
  for (int l = 0; l < NLl; ++l) addjob(dec_ca_in_w  + (size_t)l * IN3, IN3);
  for (int l = 0; l < NLl; ++l) addjob(dec_ca_out_w + (size_t)l * DD,  DD);
  for (int l = 0; l < NLl; ++l) addjob(dec_l1_w + (size_t)l * FF, FF);
  for (int l = 0; l < NLl; ++l) addjob(dec_l2_w + (size_t)l * FF, FF);
  addjob(head1_w, FF);
  addjob(head2_w, FF);

  const int ZN = 256 + STATF;
  k_zero<<<(ZN + 255) / 256, 256, 0, stream>>>(ws, ZN);
  k_abssum<<<NJOBS * 64, 256, 0, stream>>>(jobs, ABSUM);
  k_alpha<<<1, 64, 0, stream>>>(jobs, ABSUM, ALPHA, INVA);
  if (use_wq) k_quant<<<NJOBS * 128, 256, 0, stream>>>(jobs, INVA, WQ);

  auto gemm = [&](const ushort_t* Xa, const ushort_t* Xb, int n_split, int ldx,
                  const float* qe, const float* lng, const float* lnb,
                  const float* statA, const float* statB,
                  const float* W, int slot, const float* bias, const float* pos,
                  const float* res, int ldr,
                  float* o, int ldo, ushort_t* obf, ushort_t* obf2,
                  float* statOut, int N, int K, int relu) {
    dim3 grid(N / NT, Mm / MT);
    const short* wq = use_wq ? WQ + (size_t)jobs.off[slot] : nullptr;
    const float* wr = use_wq ? nullptr : W;
    k_gemm_mfma<<<grid, 256, 0, stream>>>(Xa, Xb, n_split, ldx, qe, query_idx,
                                          lng, lnb, statA, statB,
                                          wr, wq, bias, pos, res, ldr,
                                          o, ldo, obf, obf2, statOut,
                                          N, K, ALPHA, INVA, slot, relu);
  };

  const float scale = 1.f / sqrtf((float)HDd);
  auto attn = [&](const float* out_w, int out_slot, float* statOut) {
    k_attn<<<dim3(Ss / 64, Bb * NHh), 256, 0, stream>>>(QKVb, CTXb, scale);
    gemm(CTXb, nullptr, 0, Dd, nullptr, nullptr, nullptr, nullptr, nullptr,
         out_w, out_slot, nullptr, nullptr, H, Dd,
         H, Dd, Hb, nullptr, statOut, Dd, Dd, 0);
  };

  const int NELEM = Mm * Dd;
  const int EB = (NELEM + 255) / 256;

  // ---- stem: H = qlinear(t)+t+pos ; stats -> T0 ----
  k_patchify<<<EB, 256, 0, stream>>>(x, SCR, SCRb);
  gemm(SCRb, nullptr, 0, Dd, nullptr, nullptr, nullptr, nullptr, nullptr,
       lin_enc_w, 0, lin_enc_b, pos_emb, SCR, Dd,
       H, Dd, Hb, nullptr, T(0), Dd, Dd, 0);

  // ---- encoder ----
  for (int l = 0; l < NLl; ++l) {
    gemm(Hb, nullptr, 0, Dd, nullptr, enc_ln1_g + l * Dd, enc_ln1_b + l * Dd,
         T(2 * l), nullptr,
         enc_in_w + (size_t)l * IN3, 1 + l,
         nullptr, nullptr, nullptr, 0,
         nullptr, 1728, QKVb, nullptr, nullptr, 1728, Dd, 0);
    attn(enc_out_w + (size_t)l * DD, 5 + l, T(2 * l + 1));
    gemm(Hb, nullptr, 0, Dd, nullptr, enc_ln2_g + l * Dd, enc_ln2_b + l * Dd,
         T(2 * l + 1), nullptr,
         enc_l1_w + (size_t)l * FF, 9 + l,
         enc_l1_b + l * HIDh, nullptr, nullptr, 0,
         nullptr, HIDh, QKVb, nullptr, nullptr, HIDh, Dd, 1);
    gemm(QKVb, nullptr, 0, HIDh, nullptr, nullptr, nullptr, nullptr, nullptr,
         enc_l2_w + (size_t)l * FF, 13 + l,
         enc_l2_b + l * Dd, nullptr, H, Dd,
         H, Dd, Hb, (l == NLl - 1) ? MEMb : nullptr, T(2 * l + 2),
         Dd, HIDh, 0);
  }

  // ---- decoder ----
  for (int l = 0; l < NLl; ++l) {
    float* ln1s = T(8 + 3 * l);
    // merged SA-in: cols [0,1152) A=LN(H)+qe (Q,K), cols [1152,1728) B=LN(H) (V)
    gemm(Hb, Hb, 2 * Dd, Dd, query_embed,
         dec_ln1_g + l * Dd, dec_ln1_b + l * Dd, ln1s, ln1s,
         dec_sa_in_w + (size_t)l * IN3, 17 + l,
         nullptr, nullptr, nullptr, 0,
         nullptr, 1728, QKVb, nullptr, nullptr, 1728, Dd, 0);
    attn(dec_sa_out_w + (size_t)l * DD, 21 + l, T(9 + 3 * l));
    // merged CA-in: cols [0,576) A=LN(H)+qe (Q), cols [576,1728) B=MEM raw (K,V)
    gemm(Hb, MEMb, Dd, Dd, query_embed,
         dec_ln2_g + l * Dd, dec_ln2_b + l * Dd, T(9 + 3 * l), nullptr,
         dec_ca_in_w + (size_t)l * IN3, 25 + l,
         nullptr, nullptr, nullptr, 0,
         nullptr, 1728, QKVb, nullptr, nullptr, 1728, Dd, 0);
    attn(dec_ca_out_w + (size_t)l * DD, 29 + l, T(10 + 3 * l));
    gemm(Hb, nullptr, 0, Dd, nullptr, dec_ln3_g + l * Dd, dec_ln3_b + l * Dd,
         T(10 + 3 * l), nullptr,
         dec_l1_w + (size_t)l * FF, 33 + l,
         dec_l1_b + l * HIDh, nullptr, nullptr, 0,
         nullptr, HIDh, QKVb, nullptr, nullptr, HIDh, Dd, 1);
    gemm(QKVb, nullptr, 0, HIDh, nullptr, nullptr, nullptr, nullptr, nullptr,
         dec_l2_w + (size_t)l * FF, 37 + l,
         dec_l2_b + l * Dd, nullptr, H, Dd,
         H, Dd, Hb, nullptr, (l < NLl - 1) ? T(11 + 3 * l) : nullptr,
         Dd, HIDh, 0);
  }

  // ---- head (no LN) ----
  gemm(Hb, nullptr, 0, Dd, nullptr, nullptr, nullptr, nullptr, nullptr,
       head1_w, 41, head1_b, nullptr, nullptr, 0,
       nullptr, HIDh, QKVb, nullptr, nullptr, HIDh, Dd, 1);
  gemm(QKVb, nullptr, 0, HIDh, nullptr, nullptr, nullptr, nullptr, nullptr,
       head2_w, 42, head2_b, nullptr, H, Dd,
       H, Dd, nullptr, nullptr, nullptr, Dd, HIDh, 0);

  // ---- output ----
  k_unpatch<<<EB, 256, 0, stream>>>(H, out);
}

// Round 8
// 1316.048 us; speedup vs baseline: 1.3270x; 1.0109x over previous
//
#include <hip/hip_runtime.h>
#include <cstddef>

#define Pp    3
#define Cc    64
#define IMGi  48
#define Gg    16
#define Dd    576
#define NHh   12
#define HDd   48
#define HIDh  2304
#define NLl   4
#define Ss    256
#define Bb    4
#define Mm    1024          // S*B tokens
#define EPSf  1e-5f
#define NJOBS 43
#define NSTAT 20            // per-site LN stat tables (sum, sumsq) per row

typedef short short8 __attribute__((ext_vector_type(8)));
typedef short short4v __attribute__((ext_vector_type(4)));
typedef float f32x4  __attribute__((ext_vector_type(4)));
typedef unsigned short ushort_t;

struct QJobs { const float* ptr[NJOBS]; int n[NJOBS]; int off[NJOBS]; };

// float -> bf16 (RNE), bit-level
__device__ __forceinline__ short f2bf(float f) {
  unsigned u = __float_as_uint(f);
  u = u + 0x7fffu + ((u >> 16) & 1u);
  return (short)(u >> 16);
}
__device__ __forceinline__ float bf2f(short s) {
  return __uint_as_float(((unsigned)(unsigned short)s) << 16);
}

// async global->LDS, 16B per lane. dst must be wave-uniform; HW adds lane*16.
typedef __attribute__((address_space(3))) unsigned lds_u32;
typedef __attribute__((address_space(1))) const unsigned glob_u32;
__device__ __forceinline__ void gload_lds16(const void* g, void* l) {
  __builtin_amdgcn_global_load_lds((glob_u32*)g, (lds_u32*)l, 16, 0, 0);
}

// ---------------- small utility kernels ----------------

__global__ void k_zero(float* p, int n) {
  int i = blockIdx.x * blockDim.x + threadIdx.x;
  if (i < n) p[i] = 0.f;
}

// 128 blocks/job, 4 independent float4 streams in flight
__global__ void k_abssum(QJobs jobs, float* absum) {
  int job = blockIdx.x >> 7, blk = blockIdx.x & 127;
  const float4* p4 = (const float4*)jobs.ptr[job];
  int n4 = jobs.n[job] >> 2;
  float s0 = 0.f, s1 = 0.f, s2 = 0.f, s3 = 0.f;
  for (int i = blk * 1024 + threadIdx.x; i < n4; i += 128 * 1024) {
    float4 v = p4[i];
    s0 += fabsf(v.x) + fabsf(v.y) + fabsf(v.z) + fabsf(v.w);
    int i1 = i + 256;
    if (i1 < n4) { float4 w = p4[i1]; s1 += fabsf(w.x) + fabsf(w.y) + fabsf(w.z) + fabsf(w.w); }
    int i2 = i + 512;
    if (i2 < n4) { float4 w = p4[i2]; s2 += fabsf(w.x) + fabsf(w.y) + fabsf(w.z) + fabsf(w.w); }
    int i3 = i + 768;
    if (i3 < n4) { float4 w = p4[i3]; s3 += fabsf(w.x) + fabsf(w.y) + fabsf(w.z) + fabsf(w.w); }
  }
  float s = (s0 + s1) + (s2 + s3);
  #pragma unroll
  for (int o = 32; o; o >>= 1) s += __shfl_xor(s, o);
  __shared__ float red[4];
  if ((threadIdx.x & 63) == 0) red[threadIdx.x >> 6] = s;
  __syncthreads();
  if (threadIdx.x == 0) atomicAdd(&absum[job], (red[0] + red[1]) + (red[2] + red[3]));
}

__global__ void k_alpha(QJobs jobs, const float* absum, float* alpha, float* inva) {
  int j = threadIdx.x;
  if (j < NJOBS) {
    float a = 2.f * (absum[j] / (float)jobs.n[j]) / sqrtf(7.f);
    alpha[j] = a;
    inva[j] = 1.f / a;
  }
}

__device__ __forceinline__ short8 quant8(const float* p, float ia) {
  const float4* p4 = (const float4*)p;
  float4 w0 = p4[0], w1 = p4[1];
  short8 bv;
  bv[0] = f2bf(rintf(fminf(7.f, fmaxf(-8.f, w0.x * ia))));
  bv[1] = f2bf(rintf(fminf(7.f, fmaxf(-8.f, w0.y * ia))));
  bv[2] = f2bf(rintf(fminf(7.f, fmaxf(-8.f, w0.z * ia))));
  bv[3] = f2bf(rintf(fminf(7.f, fmaxf(-8.f, w0.w * ia))));
  bv[4] = f2bf(rintf(fminf(7.f, fmaxf(-8.f, w1.x * ia))));
  bv[5] = f2bf(rintf(fminf(7.f, fmaxf(-8.f, w1.y * ia))));
  bv[6] = f2bf(rintf(fminf(7.f, fmaxf(-8.f, w1.z * ia))));
  bv[7] = f2bf(rintf(fminf(7.f, fmaxf(-8.f, w1.w * ia))));
  return bv;
}

// pre-quantize all weights: wq = bf16( rint(clamp(w/alpha,-8,7)) ), 4-deep MLP
__global__ void k_quant(QJobs jobs, const float* __restrict__ inva, short* __restrict__ wq) {
  int job = blockIdx.x >> 7, blk = blockIdx.x & 127;
  const float* p = jobs.ptr[job];
  int n8 = jobs.n[job] >> 3;
  short* dst = wq + (size_t)jobs.off[job];
  float ia = inva[job];
  for (int i = blk * 1024 + threadIdx.x; i < n8; i += 128 * 1024) {
    *(short8*)(dst + (size_t)i * 8) = quant8(p + (size_t)i * 8, ia);
    int i1 = i + 256;
    if (i1 < n8) *(short8*)(dst + (size_t)i1 * 8) = quant8(p + (size_t)i1 * 8, ia);
    int i2 = i + 512;
    if (i2 < n8) *(short8*)(dst + (size_t)i2 * 8) = quant8(p + (size_t)i2 * 8, ia);
    int i3 = i + 768;
    if (i3 < n8) *(short8*)(dst + (size_t)i3 * 8) = quant8(p + (size_t)i3 * 8, ia);
  }
}

// x:(B,C,48,48) fp32 -> t:(S,B,D) fp32 + bf16 ; row = s*B+b
__global__ void k_patchify(const float* __restrict__ x, float* __restrict__ t,
                           ushort_t* __restrict__ tb) {
  int i = blockIdx.x * 256 + threadIdx.x;
  if (i >= Mm * Dd) return;
  int d = i % Dd, row = i / Dd;
  int b = row % Bb, s = row / Bb;
  int c = d / 9, r = d % 9;
  int p1 = r / 3, p2 = r % 3;
  int g1 = s / Gg, g2 = s % Gg;
  float v = x[((size_t)(b * Cc + c) * IMGi + (g1 * Pp + p1)) * IMGi + (g2 * Pp + p2)];
  t[i] = v;
  tb[i] = (ushort_t)f2bf(v);
}

// H:(S,B,D) fp32 -> out:(B,C,48,48) fp32
__global__ void k_unpatch(const float* __restrict__ h, float* __restrict__ out) {
  int i = blockIdx.x * 256 + threadIdx.x;
  if (i >= Bb * Cc * IMGi * IMGi) return;
  int j = i % IMGi, t = i / IMGi;
  int r = t % IMGi; t /= IMGi;
  int c = t % Cc;
  int b = t / Cc;
  int g1 = r / Pp, p1 = r % Pp, g2 = j / Pp, p2 = j % Pp;
  int s = g1 * Gg + g2;
  int d = c * 9 + p1 * 3 + p2;
  out[i] = h[(size_t)(s * Bb + b) * Dd + d];
}

// ---------------- MFMA GEMM ------------------------------------------------
// Block: 256 thr (4 waves), tile 64x64, wave tile 32x32 (4x mfma 16x16x32).
// K multiple of 288. DB=1: 76 KB LDS, 2 blocks/CU (K=576 shapes).
// DB=2: double-buffered whole-K pipeline, 152 KB LDS, 1 block/CU (K=2304):
//   stage(0); sync; { stage(c+1 -> other buf); compute(c); sync; } ...
//   -> one barrier/chunk, staging latency hidden under compute.
// A and B both bf16 in padded (304-short) swizzled LDS images.
#define MT 64
#define NT 64
#define KC 288
#define LDKB 304   // row stride in shorts (608 B)
#define PANEL (NT * LDKB)
#define BCHUNKS 38 // 64*304 shorts / 512 shorts-per-1KB-chunk

__device__ __forceinline__ int bswz(int row, int colByte) {
  return row * (LDKB * 2) + (colByte ^ (((row >> 2) & 3) << 4));
}

// async panel stage: 64 rows x 288 shorts from base (row stride ld shorts)
__device__ __forceinline__ void stage_async(const ushort_t* base, int ld,
                                            char* lds, int wave, int lane) {
  #pragma unroll
  for (int j = 0; j < 10; ++j) {
    const int c = wave * 10 + j;          // wave-uniform chunk id
    if (c < BCHUNKS) {
      const int p = c * 512 + lane * 8;   // physical short index
      const int prow = p / LDKB;
      const int pcol2 = (p % LDKB) * 2;   // physical byte col in [0,608)
      const int lcol = pcol2 ^ (((prow >> 2) & 3) << 4);
      const ushort_t* src = (lcol < 576)
        ? base + (size_t)prow * ld + (lcol >> 1)
        : base;                           // pad slot, never read
      gload_lds16(src, lds + c * 1024);
    }
  }
}

template <int DB>
__global__ __launch_bounds__(256)
void k_gemm_mfma(const ushort_t* __restrict__ Xa, const ushort_t* __restrict__ Xb,
                 int n_split, int ldx,
                 const float* __restrict__ qe, const int* __restrict__ qidx,
                 const float* __restrict__ lng, const float* __restrict__ lnb,
                 const float* __restrict__ statA, const float* __restrict__ statB,
                 const float* __restrict__ Wraw, const short* __restrict__ Wq,
                 const float* __restrict__ bias, const float* __restrict__ pos,
                 const float* res, int ldr,
                 float* out, int ldo,
                 ushort_t* outbf, ushort_t* outbf2, float* statOut,
                 int N, int K,
                 const float* __restrict__ alpha_p, const float* __restrict__ inva_p,
                 int slot, int relu)
{
  __shared__ short As[DB * PANEL];
  __shared__ short Bs[DB * PANEL];
  const int tid  = threadIdx.x;
  const int wave = tid >> 6, lane = tid & 63;
  const int quad = lane >> 4, l15 = lane & 15;
  const int tile_m = blockIdx.y * MT, tile_n = blockIdx.x * NT;
  const int m_off = (wave >> 1) * 32, n_off = (wave & 1) * 32;
  const int sr = tid >> 2;           // staging row 0..63
  const int sc = (tid & 3) * 8;      // staging col start (shorts), stride 32
  const float inva = inva_p[slot];

  const bool isA = (!Xb || tile_n < n_split);
  const ushort_t* X = isA ? Xa : Xb;
  const bool addqe = (qe != nullptr) && isA;
  const float* stat = isA ? statA : statB;
  const bool a_reg = (stat != nullptr) || addqe;
  size_t qe_off = 0;
  if (addqe) qe_off = (size_t)qidx[0] * ((size_t)Ss * Dd);

  // per-row LN params from stat table (single read per staging thread)
  float mean = 0.f, sinv = 1.f;
  if (stat) {
    float2 st = *(const float2*)&stat[2 * (tile_m + sr)];
    mean = st.x * (1.f / (float)Dd);
    float var = st.y * (1.f / (float)Dd) - mean * mean;
    sinv = rsqrtf(var + EPSf);
  }

  f32x4 acc00 = {0,0,0,0}, acc01 = {0,0,0,0}, acc10 = {0,0,0,0}, acc11 = {0,0,0,0};

  auto STAGE = [&](int kc, int buf) {
    short* Asb = As + buf * PANEL;
    short* Bsb = Bs + buf * PANEL;
    // ---- B panel ----
    if (Wq) {
      stage_async((const ushort_t*)Wq + (size_t)tile_n * K + kc, K,
                  (char*)Bsb, wave, lane);
    } else {
      const float* wr = Wraw + (size_t)(tile_n + sr) * K + kc;
      #pragma unroll
      for (int j = 0; j < 9; ++j) {
        const int k = sc + j * 32;
        short8 bv;
        bv = quant8(wr + k, inva);
        *(short8*)((char*)Bsb + bswz(sr, k * 2)) = bv;
      }
    }
    // ---- A panel ----
    if (!a_reg) {
      stage_async(X + (size_t)tile_m * ldx + kc, ldx, (char*)Asb, wave, lane);
    } else {
      const int arow = tile_m + sr;
      const ushort_t* xr = X + (size_t)arow * ldx + kc;
      const float* qr = addqe ? (qe + qe_off + (size_t)(arow >> 2) * Dd + kc) : nullptr;
      #pragma unroll
      for (int j = 0; j < 9; ++j) {
        const int k = sc + j * 32;
        short8 xv = *(const short8*)(xr + k);
        float a[8];
        #pragma unroll
        for (int e = 0; e < 8; ++e) a[e] = bf2f(xv[e]);
        if (stat) {
          float4 g0 = *(const float4*)(lng + kc + k);
          float4 g1 = *(const float4*)(lng + kc + k + 4);
          float4 b0 = *(const float4*)(lnb + kc + k);
          float4 b1 = *(const float4*)(lnb + kc + k + 4);
          a[0] = (a[0] - mean) * sinv * g0.x + b0.x;
          a[1] = (a[1] - mean) * sinv * g0.y + b0.y;
          a[2] = (a[2] - mean) * sinv * g0.z + b0.z;
          a[3] = (a[3] - mean) * sinv * g0.w + b0.w;
          a[4] = (a[4] - mean) * sinv * g1.x + b1.x;
          a[5] = (a[5] - mean) * sinv * g1.y + b1.y;
          a[6] = (a[6] - mean) * sinv * g1.z + b1.z;
          a[7] = (a[7] - mean) * sinv * g1.w + b1.w;
        }
        if (addqe) {
          float4 q0 = *(const float4*)(qr + k);
          float4 q1 = *(const float4*)(qr + k + 4);
          a[0] += q0.x; a[1] += q0.y; a[2] += q0.z; a[3] += q0.w;
          a[4] += q1.x; a[5] += q1.y; a[6] += q1.z; a[7] += q1.w;
        }
        short8 av;
        #pragma unroll
        for (int e = 0; e < 8; ++e) av[e] = f2bf(a[e]);
        *(short8*)((char*)Asb + bswz(sr, k * 2)) = av;
      }
    }
  };

  auto COMPUTE = [&](int buf) {
    const short* Asb = As + buf * PANEL;
    const short* Bsb = Bs + buf * PANEL;
    #pragma unroll 3
    for (int ks = 0; ks < KC / 32; ++ks) {
      const int kb = ks * 32 + quad * 8;
      short8 af0 = *(const short8*)((const char*)Asb + bswz(m_off + l15, kb * 2));
      short8 af1 = *(const short8*)((const char*)Asb + bswz(m_off + 16 + l15, kb * 2));
      short8 bf0 = *(const short8*)((const char*)Bsb + bswz(n_off + l15, kb * 2));
      short8 bf1 = *(const short8*)((const char*)Bsb + bswz(n_off + 16 + l15, kb * 2));
      acc00 = __builtin_amdgcn_mfma_f32_16x16x32_bf16(af0, bf0, acc00, 0, 0, 0);
      acc01 = __builtin_amdgcn_mfma_f32_16x16x32_bf16(af0, bf1, acc01, 0, 0, 0);
      acc10 = __builtin_amdgcn_mfma_f32_16x16x32_bf16(af1, bf0, acc10, 0, 0, 0);
      acc11 = __builtin_amdgcn_mfma_f32_16x16x32_bf16(af1, bf1, acc11, 0, 0, 0);
    }
  };

  const int nc = K / KC;
  if (DB == 2) {
    STAGE(0, 0);
    __syncthreads();
    for (int c = 0; c < nc; ++c) {
      if (c + 1 < nc) STAGE((c + 1) * KC, (c + 1) & 1);
      COMPUTE(c & 1);
      __syncthreads();
    }
  } else {
    for (int c = 0; c < nc; ++c) {
      STAGE(c * KC, 0);
      __syncthreads();
      COMPUTE(0);
      __syncthreads();
    }
  }

  // ---- epilogue ----
  const float a_s = alpha_p[slot];
  const int rowb = tile_m + m_off + quad * 4;
  const int colb = tile_n + n_off + l15;
  f32x4 accs[4] = {acc00, acc01, acc10, acc11};
  float vsum[2][4], vsq[2][4];
  #pragma unroll
  for (int rt = 0; rt < 2; ++rt)
    #pragma unroll
    for (int r = 0; r < 4; ++r) { vsum[rt][r] = 0.f; vsq[rt][r] = 0.f; }

  #pragma unroll
  for (int t = 0; t < 4; ++t) {
    int row0 = rowb + ((t >> 1) * 16);
    int col  = colb + ((t & 1) * 16);
    float bv = bias ? bias[col] : 0.f;
    #pragma unroll
    for (int r = 0; r < 4; ++r) {
      int row = row0 + r;
      float v = accs[t][r] * a_s + bv;
      if (res) v += res[(size_t)row * ldr + col];
      if (pos) v += pos[(size_t)(row >> 2) * Dd + col];
      if (relu) v = fmaxf(v, 0.f);
      if (out)    out[(size_t)row * ldo + col] = v;
      if (outbf)  outbf[(size_t)row * ldo + col]  = (ushort_t)f2bf(v);
      if (outbf2) outbf2[(size_t)row * ldo + col] = (ushort_t)f2bf(v);
      vsum[t >> 1][r] += v;
      vsq[t >> 1][r]  += v * v;
    }
  }

  // ---- per-row LN-stat accumulation for downstream consumers ----
  if (statOut) {
    #pragma unroll
    for (int rt = 0; rt < 2; ++rt) {
      #pragma unroll
      for (int r = 0; r < 4; ++r) {
        float s = vsum[rt][r], q = vsq[rt][r];
        #pragma unroll
        for (int o = 1; o < 16; o <<= 1) {
          s += __shfl_xor(s, o);
          q += __shfl_xor(q, o);
        }
        if (l15 == 0) {
          int row = rowb + rt * 16 + r;
          atomicAdd(&statOut[2 * row],     s);
          atomicAdd(&statOut[2 * row + 1], q);
        }
      }
    }
  }
}

// ---------------- fused flash attention (bf16 in, bf16 out) ----------------
__global__ __launch_bounds__(256)
void k_attn(const ushort_t* __restrict__ QKV, ushort_t* __restrict__ ctx, float scale) {
  __shared__ short Ks[256][72];   // [ki][d]  d 48..63 zero-padded
  __shared__ short Qs[64][72];    // [qi][d]  zero-padded
  __shared__ short Vt[48][264];   // [d][ki]
  __shared__ short Pq[64][264];   // [qi][ki]
  const int qt = blockIdx.x;
  const int b  = blockIdx.y / NHh, h = blockIdx.y % NHh;
  const int tid = threadIdx.x;
  const int w = tid >> 6, lane = tid & 63, quad = lane >> 4, l15 = lane & 15;

  {
    const ushort_t* kp = QKV + (size_t)(tid * Bb + b) * 1728 + Dd + h * HDd;
    #pragma unroll
    for (int d0 = 0; d0 < 48; d0 += 8)
      *(short8*)&Ks[tid][d0] = *(const short8*)(kp + d0);
    short4v z = {0, 0, 0, 0};
    *(short4v*)&Ks[tid][48] = z; *(short4v*)&Ks[tid][52] = z;
    *(short4v*)&Ks[tid][56] = z; *(short4v*)&Ks[tid][60] = z;
    const ushort_t* vp = QKV + (size_t)(tid * Bb + b) * 1728 + 2 * Dd + h * HDd;
    #pragma unroll
    for (int d0 = 0; d0 < 48; d0 += 8) {
      short8 v = *(const short8*)(vp + d0);
      #pragma unroll
      for (int e = 0; e < 8; ++e) Vt[d0 + e][tid] = v[e];
    }
    if (tid < 64) {
      const ushort_t* qp = QKV + (size_t)((qt * 64 + tid) * Bb + b) * 1728 + h * HDd;
      #pragma unroll
      for (int d0 = 0; d0 < 48; d0 += 8)
        *(short8*)&Qs[tid][d0] = *(const short8*)(qp + d0);
      *(short4v*)&Qs[tid][48] = z; *(short4v*)&Qs[tid][52] = z;
      *(short4v*)&Qs[tid][56] = z; *(short4v*)&Qs[tid][60] = z;
    }
  }
  __syncthreads();

  short8 bq0 = *(short8*)&Qs[w * 16 + l15][quad * 8];
  short8 bq1 = *(short8*)&Qs[w * 16 + l15][32 + quad * 8];
  f32x4 sf[16];
  #pragma unroll
  for (int mt = 0; mt < 16; ++mt) {
    f32x4 acc = {0, 0, 0, 0};
    short8 a0 = *(short8*)&Ks[mt * 16 + l15][quad * 8];
    short8 a1 = *(short8*)&Ks[mt * 16 + l15][32 + quad * 8];
    acc = __builtin_amdgcn_mfma_f32_16x16x32_bf16(a0, bq0, acc, 0, 0, 0);
    acc = __builtin_amdgcn_mfma_f32_16x16x32_bf16(a1, bq1, acc, 0, 0, 0);
    sf[mt] = acc;
  }

  float mx = -1e30f;
  #pragma unroll
  for (int mt = 0; mt < 16; ++mt)
    #pragma unroll
    for (int r = 0; r < 4; ++r) {
      sf[mt][r] *= scale;
      mx = fmaxf(mx, sf[mt][r]);
    }
  mx = fmaxf(mx, __shfl_xor(mx, 16));
  mx = fmaxf(mx, __shfl_xor(mx, 32));
  float sum = 0.f;
  #pragma unroll
  for (int mt = 0; mt < 16; ++mt)
    #pragma unroll
    for (int r = 0; r < 4; ++r) {
      float e = __expf(sf[mt][r] - mx);
      sf[mt][r] = e;
      sum += e;
    }
  sum += __shfl_xor(sum, 16);
  sum += __shfl_xor(sum, 32);
  float inv = 1.f / sum;

  #pragma unroll
  for (int mt = 0; mt < 16; ++mt) {
    short4v p = { f2bf(sf[mt][0] * inv), f2bf(sf[mt][1] * inv),
                  f2bf(sf[mt][2] * inv), f2bf(sf[mt][3] * inv) };
    *(short4v*)&Pq[w * 16 + l15][mt * 16 + quad * 4] = p;
  }
  __syncthreads();

  f32x4 of0 = {0,0,0,0}, of1 = {0,0,0,0}, of2 = {0,0,0,0};
  #pragma unroll
  for (int kt = 0; kt < 8; ++kt) {
    short8 a = *(short8*)&Pq[w * 16 + l15][kt * 32 + quad * 8];
    short8 b0 = *(short8*)&Vt[l15][kt * 32 + quad * 8];
    short8 b1 = *(short8*)&Vt[16 + l15][kt * 32 + quad * 8];
    short8 b2 = *(short8*)&Vt[32 + l15][kt * 32 + quad * 8];
    of0 = __builtin_amdgcn_mfma_f32_16x16x32_bf16(a, b0, of0, 0, 0, 0);
    of1 = __builtin_amdgcn_mfma_f32_16x16x32_bf16(a, b1, of1, 0, 0, 0);
    of2 = __builtin_amdgcn_mfma_f32_16x16x32_bf16(a, b2, of2, 0, 0, 0);
  }
  const int qg = qt * 64 + w * 16 + quad * 4;
  #pragma unroll
  for (int r = 0; r < 4; ++r) {
    ushort_t* cr = ctx + (size_t)((qg + r) * Bb + b) * Dd + h * HDd + l15;
    cr[0]  = (ushort_t)f2bf(of0[r]);
    cr[16] = (ushort_t)f2bf(of1[r]);
    cr[32] = (ushort_t)f2bf(of2[r]);
  }
}

// ---------------- host ----------------

extern "C" void kernel_launch(void* const* d_in, const int* in_sizes, int n_in,
                              void* d_out, int out_size, void* d_ws, size_t ws_size,
                              hipStream_t stream) {
  (void)in_sizes; (void)n_in; (void)out_size;
  const float* x            = (const float*)d_in[0];
  const float* lin_enc_w    = (const float*)d_in[1];
  const float* lin_enc_b    = (const float*)d_in[2];
  const float* pos_emb      = (const float*)d_in[3];
  const float* query_embed  = (const float*)d_in[4];
  const float* enc_in_w     = (const float*)d_in[5];
  const float* enc_out_w    = (const float*)d_in[6];
  const float* enc_l1_w     = (const float*)d_in[7];
  const float* enc_l1_b     = (const float*)d_in[8];
  const float* enc_l2_w     = (const float*)d_in[9];
  const float* enc_l2_b     = (const float*)d_in[10];
  const float* enc_ln1_g    = (const float*)d_in[11];
  const float* enc_ln1_b    = (const float*)d_in[12];
  const float* enc_ln2_g    = (const float*)d_in[13];
  const float* enc_ln2_b    = (const float*)d_in[14];
  const float* dec_sa_in_w  = (const float*)d_in[15];
  const float* dec_sa_out_w = (const float*)d_in[16];
  const float* dec_ca_in_w  = (const float*)d_in[17];
  const float* dec_ca_out_w = (const float*)d_in[18];
  const float* dec_l1_w     = (const float*)d_in[19];
  const float* dec_l1_b     = (const float*)d_in[20];
  const float* dec_l2_w     = (const float*)d_in[21];
  const float* dec_l2_b     = (const float*)d_in[22];
  const float* dec_ln1_g    = (const float*)d_in[23];
  const float* dec_ln1_b    = (const float*)d_in[24];
  const float* dec_ln2_g    = (const float*)d_in[25];
  const float* dec_ln2_b    = (const float*)d_in[26];
  const float* dec_ln3_g    = (const float*)d_in[27];
  const float* dec_ln3_b    = (const float*)d_in[28];
  const float* head1_w      = (const float*)d_in[29];
  const float* head1_b      = (const float*)d_in[30];
  const float* head2_w      = (const float*)d_in[31];
  const float* head2_b      = (const float*)d_in[32];
  const int*   query_idx    = (const int*)d_in[33];
  float* out = (float*)d_out;

  const int DD  = Dd * Dd;
  const int IN3 = 3 * Dd * Dd;
  const int FF  = HIDh * Dd;
  const int MD  = Mm * Dd;

  float* ws = (float*)d_ws;
  float* ABSUM = ws;
  float* ALPHA = ws + 64;
  float* INVA  = ws + 128;
  float* STAT  = ws + 256;                 // NSTAT tables x 1024 rows x 2
  const int STATF = NSTAT * Mm * 2;        // 40960 floats
  float* H   = STAT + STATF;               // fp32 residual master
  float* SCR = H + MD;                     // fp32 patchify (stem residual)
  ushort_t* Hb   = (ushort_t*)(SCR + MD);  // bf16 companions / activations
  ushort_t* SCRb = Hb + MD;
  ushort_t* MEMb = SCRb + MD;
  ushort_t* CTXb = MEMb + MD;
  ushort_t* QKVb = CTXb + MD;              // Mm x 1728 (qkv) / Mm x 2304 (ffn)
  size_t act_bytes = (256 + (size_t)STATF + 2 * (size_t)MD) * 4
                   + (4 * (size_t)MD + (size_t)Mm * HIDh) * 2;
  short* WQ = (short*)(QKVb + (size_t)Mm * HIDh);
  const size_t WQ_ELEMS = (size_t)DD + 4 * ((size_t)IN3 + DD + FF + FF)
                        + 4 * ((size_t)IN3 + DD + IN3 + DD + FF + FF)
                        + 2 * (size_t)FF;
  const bool use_wq = ws_size >= act_bytes + WQ_ELEMS * 2;

  auto T = [&](int i) { return STAT + (size_t)i * (Mm * 2); };

  QJobs jobs;
  int j = 0; int off = 0;
  auto addjob = [&](const float* p, int n) { jobs.ptr[j] = p; jobs.n[j] = n; jobs.off[j] = off; off += n; j++; };
  addjob(lin_enc_w, DD);
  for (int l = 0; l < NLl; ++l) addjob(enc_in_w  + (size_t)l * IN3, IN3);
  for (int l = 0; l < NLl; ++l) addjob(enc_out_w + (size_t)l * DD,  DD);
  for (int l = 0; l < NLl; ++l) addjob(enc_l1_w  + (size_t)l * FF,  FF);
  for (int l = 0; l < NLl; ++l) addjob(enc_l2_w  + (size_t)l * FF,  FF);
  for (int l = 0; l < NLl; ++l) addjob(dec_sa_in_w  + (size_t)l * IN3, IN3);
  for (int l = 0; l < NLl; ++l) addjob(dec_sa_out_w + (size_t)l * DD,  DD);
  for (int l = 0; l < NLl; ++l) addjob(dec_ca_in_w  + (size_t)l * IN3, IN3);
  for (int l = 0; l < NLl; ++l) addjob(dec_ca_out_w + (size_t)l * DD,  DD);
  for (int l = 0; l < NLl; ++l) addjob(dec_l1_w + (size_t)l * FF, FF);
  for (int l = 0; l < NLl; ++l) addjob(dec_l2_w + (size_t)l * FF, FF);
  addjob(head1_w, FF);
  addjob(head2_w, FF);

  const int ZN = 256 + STATF;
  k_zero<<<(ZN + 255) / 256, 256, 0, stream>>>(ws, ZN);
  k_abssum<<<NJOBS * 128, 256, 0, stream>>>(jobs, ABSUM);
  k_alpha<<<1, 64, 0, stream>>>(jobs, ABSUM, ALPHA, INVA);
  if (use_wq) k_quant<<<NJOBS * 128, 256, 0, stream>>>(jobs, INVA, WQ);

  auto gemm = [&](const ushort_t* Xa, const ushort_t* Xb, int n_split, int ldx,
                  const float* qe, const float* lng, const float* lnb,
                  const float* statA, const float* statB,
                  const float* W, int slot, const float* bias, const float* pos,
                  const float* res, int ldr,
                  float* o, int ldo, ushort_t* obf, ushort_t* obf2,
                  float* statOut, int N, int K, int relu) {
    dim3 grid(N / NT, Mm / MT);
    const short* wq = use_wq ? WQ + (size_t)jobs.off[slot] : nullptr;
    const float* wr = use_wq ? nullptr : W;
    if (K > 2 * KC)
      k_gemm_mfma<2><<<grid, 256, 0, stream>>>(Xa, Xb, n_split, ldx, qe, query_idx,
                                               lng, lnb, statA, statB,
                                               wr, wq, bias, pos, res, ldr,
                                               o, ldo, obf, obf2, statOut,
                                               N, K, ALPHA, INVA, slot, relu);
    else
      k_gemm_mfma<1><<<grid, 256, 0, stream>>>(Xa, Xb, n_split, ldx, qe, query_idx,
                                               lng, lnb, statA, statB,
                                               wr, wq, bias, pos, res, ldr,
                                               o, ldo, obf, obf2, statOut,
                                               N, K, ALPHA, INVA, slot, relu);
  };

  const float scale = 1.f / sqrtf((float)HDd);
  auto attn = [&](const float* out_w, int out_slot, float* statOut) {
    k_attn<<<dim3(Ss / 64, Bb * NHh), 256, 0, stream>>>(QKVb, CTXb, scale);
    gemm(CTXb, nullptr, 0, Dd, nullptr, nullptr, nullptr, nullptr, nullptr,
         out_w, out_slot, nullptr, nullptr, H, Dd,
         H, Dd, Hb, nullptr, statOut, Dd, Dd, 0);
  };

  const int NELEM = Mm * Dd;
  const int EB = (NELEM + 255) / 256;

  // ---- stem: H = qlinear(t)+t+pos ; stats -> T0 ----
  k_patchify<<<EB, 256, 0, stream>>>(x, SCR, SCRb);
  gemm(SCRb, nullptr, 0, Dd, nullptr, nullptr, nullptr, nullptr, nullptr,
       lin_enc_w, 0, lin_enc_b, pos_emb, SCR, Dd,
       H, Dd, Hb, nullptr, T(0), Dd, Dd, 0);

  // ---- encoder ----
  for (int l = 0; l < NLl; ++l) {
    gemm(Hb, nullptr, 0, Dd, nullptr, enc_ln1_g + l * Dd, enc_ln1_b + l * Dd,
         T(2 * l), nullptr,
         enc_in_w + (size_t)l * IN3, 1 + l,
         nullptr, nullptr, nullptr, 0,
         nullptr, 1728, QKVb, nullptr, nullptr, 1728, Dd, 0);
    attn(enc_out_w + (size_t)l * DD, 5 + l, T(2 * l + 1));
    gemm(Hb, nullptr, 0, Dd, nullptr, enc_ln2_g + l * Dd, enc_ln2_b + l * Dd,
         T(2 * l + 1), nullptr,
         enc_l1_w + (size_t)l * FF, 9 + l,
         enc_l1_b + l * HIDh, nullptr, nullptr, 0,
         nullptr, HIDh, QKVb, nullptr, nullptr, HIDh, Dd, 1);
    gemm(QKVb, nullptr, 0, HIDh, nullptr, nullptr, nullptr, nullptr, nullptr,
         enc_l2_w + (size_t)l * FF, 13 + l,
         enc_l2_b + l * Dd, nullptr, H, Dd,
         H, Dd, Hb, (l == NLl - 1) ? MEMb : nullptr, T(2 * l + 2),
         Dd, HIDh, 0);
  }

  // ---- decoder ----
  for (int l = 0; l < NLl; ++l) {
    float* ln1s = T(8 + 3 * l);
    // merged SA-in: cols [0,1152) A=LN(H)+qe (Q,K), cols [1152,1728) B=LN(H) (V)
    gemm(Hb, Hb, 2 * Dd, Dd, query_embed,
         dec_ln1_g + l * Dd, dec_ln1_b + l * Dd, ln1s, ln1s,
         dec_sa_in_w + (size_t)l * IN3, 17 + l,
         nullptr, nullptr, nullptr, 0,
         nullptr, 1728, QKVb, nullptr, nullptr, 1728, Dd, 0);
    attn(dec_sa_out_w + (size_t)l * DD, 21 + l, T(9 + 3 * l));
    // merged CA-in: cols [0,576) A=LN(H)+qe (Q), cols [576,1728) B=MEM raw (K,V)
    gemm(Hb, MEMb, Dd, Dd, query_embed,
         dec_ln2_g + l * Dd, dec_ln2_b + l * Dd, T(9 + 3 * l), nullptr,
         dec_ca_in_w + (size_t)l * IN3, 25 + l,
         nullptr, nullptr, nullptr, 0,
         nullptr, 1728, QKVb, nullptr, nullptr, 1728, Dd, 0);
    attn(dec_ca_out_w + (size_t)l * DD, 29 + l, T(10 + 3 * l));
    gemm(Hb, nullptr, 0, Dd, nullptr, dec_ln3_g + l * Dd, dec_ln3_b + l * Dd,
         T(10 + 3 * l), nullptr,
         dec_l1_w + (size_t)l * FF, 33 + l,
         dec_l1_b + l * HIDh, nullptr, nullptr, 0,
         nullptr, HIDh, QKVb, nullptr, nullptr, HIDh, Dd, 1);
    gemm(QKVb, nullptr, 0, HIDh, nullptr, nullptr, nullptr, nullptr, nullptr,
         dec_l2_w + (size_t)l * FF, 37 + l,
         dec_l2_b + l * Dd, nullptr, H, Dd,
         H, Dd, Hb, nullptr, (l < NLl - 1) ? T(11 + 3 * l) : nullptr,
         Dd, HIDh, 0);
  }

  // ---- head (no LN) ----
  gemm(Hb, nullptr, 0, Dd, nullptr, nullptr, nullptr, nullptr, nullptr,
       head1_w, 41, head1_b, nullptr, nullptr, 0,
       nullptr, HIDh, QKVb, nullptr, nullptr, HIDh, Dd, 1);
  gemm(QKVb, nullptr, 0, HIDh, nullptr, nullptr, nullptr, nullptr, nullptr,
       head2_w, 42, head2_b, nullptr, H, Dd,
       H, Dd, nullptr, nullptr, nullptr, Dd, HIDh, 0);

  // ---- output ----
  k_unpatch<<<EB, 256, 0, stream>>>(H, out);
}